// Round 23
// baseline (375.929 us; speedup 1.0000x reference)
//
#include <hip/hip_runtime.h>
#include <hip/hip_bf16.h>
#include <math.h>

// Problem constants
#define B_    2
#define L_    2048
#define DM_   1024      // d_model
#define DI_   2048      // d_inner
#define DS_   16        // d_state
#define DTR_  64        // dt_rank
#define NXZ_  4096      // 2*d_inner
#define NDBC_ 96        // dt_rank + 2*d_state

#define NSEG   64
#define SEGLEN 32
#define CT     16       // timesteps staged per chunk
#define KS_    8        // xproj split-K factor
#define KO_    4        // out_proj split-K factor (bf16 partials make 4 cheap)

#define LOG2E 1.4426950408889634f

typedef __attribute__((ext_vector_type(8))) short bf16x8;
typedef __attribute__((ext_vector_type(4))) float f32x4;

__device__ __forceinline__ void gload_lds16(const void* g, void* l) {
    __builtin_amdgcn_global_load_lds(
        (const __attribute__((address_space(1))) void*)g,
        (__attribute__((address_space(3))) void*)l,
        16, 0, 0);
}

__device__ __forceinline__ float bf2f(short s) {
    union { unsigned u; float f; } x;
    x.u = ((unsigned)(unsigned short)s) << 16;
    return x.f;
}

// ---------------- LayerNorm (one block per row) -> bf16 out ----------------
__global__ __launch_bounds__(256)
void ln_kernel(const float* __restrict__ x,
               const float* __restrict__ gamma,
               const float* __restrict__ beta,
               __hip_bfloat16* __restrict__ out)
{
    int row = blockIdx.x;
    int t = threadIdx.x;
    const float* xr = x + (size_t)row * DM_;
    float4 v = ((const float4*)xr)[t];
    float s  = v.x + v.y + v.z + v.w;
    float ss = v.x*v.x + v.y*v.y + v.z*v.z + v.w*v.w;
    #pragma unroll
    for (int m = 1; m < 64; m <<= 1) {
        s  += __shfl_xor(s,  m, 64);
        ss += __shfl_xor(ss, m, 64);
    }
    __shared__ float as_[4], ass_[4];
    int w = t >> 6;
    if ((t & 63) == 0) { as_[w] = s; ass_[w] = ss; }
    __syncthreads();
    s  = as_[0] + as_[1] + as_[2] + as_[3];
    ss = ass_[0] + ass_[1] + ass_[2] + ass_[3];
    float mu  = s * (1.0f / DM_);
    float var = ss * (1.0f / DM_) - mu * mu;
    float inv = rsqrtf(var + 1e-5f);
    float4 g  = ((const float4*)gamma)[t];
    float4 bt = ((const float4*)beta)[t];
    __hip_bfloat16 ob[4];
    ob[0] = __float2bfloat16((v.x - mu) * inv * g.x + bt.x);
    ob[1] = __float2bfloat16((v.y - mu) * inv * g.y + bt.y);
    ob[2] = __float2bfloat16((v.z - mu) * inv * g.z + bt.z);
    ob[3] = __float2bfloat16((v.w - mu) * inv * g.w + bt.w);
    ((ushort4*)(out + (size_t)row * DM_))[t] = *(const ushort4*)ob;
}

// ---------------- merged weight convert (all 8 weights, both dirs) ---------
__global__ __launch_bounds__(256)
void cvt_all(const float* __restrict__ inw_f, const float* __restrict__ inw_b,
             const float* __restrict__ ow_f,  const float* __restrict__ ow_b,
             const float* __restrict__ xp_f,  const float* __restrict__ xp_b,
             const float* __restrict__ dw_f,  const float* __restrict__ dw_b,
             __hip_bfloat16* __restrict__ win,
             __hip_bfloat16* __restrict__ wocat,
             __hip_bfloat16* __restrict__ xpw,
             __hip_bfloat16* __restrict__ dtw)
{
    const int N_WIN = 2 * NXZ_ * DM_;
    const int N_WO  = DM_ * NXZ_;
    const int N_XP  = 2 * NDBC_ * DI_;
    int i = (blockIdx.x * 256 + threadIdx.x) * 4;
    const float* s;
    __hip_bfloat16* dst;
    int dj;
    if (i < N_WIN) {
        int half = NXZ_ * DM_;
        s = (i < half) ? inw_f + i : inw_b + (i - half);
        dst = win; dj = i;
    } else if (i < N_WIN + N_WO) {
        int jj = i - N_WIN;
        int n = jj >> 12, c = jj & 4095;
        int dir = c >> 11, k = c & 2047;
        s = (dir ? ow_b : ow_f) + (size_t)n * DI_ + k;
        dst = wocat; dj = jj;
    } else if (i < N_WIN + N_WO + N_XP) {
        int jj = i - N_WIN - N_WO;
        int half = NDBC_ * DI_;
        s = (jj < half) ? xp_f + jj : xp_b + (jj - half);
        dst = xpw; dj = jj;
    } else {
        int jj = i - N_WIN - N_WO - N_XP;
        int half = DI_ * DTR_;
        s = (jj < half) ? dw_f + jj : dw_b + (jj - half);
        dst = dtw; dj = jj;
    }
    float4 v = *(const float4*)s;
    __hip_bfloat16 ob[4];
    ob[0] = __float2bfloat16(v.x);
    ob[1] = __float2bfloat16(v.y);
    ob[2] = __float2bfloat16(v.z);
    ob[3] = __float2bfloat16(v.w);
    *(ushort4*)(dst + dj) = *(const ushort4*)ob;
}

// ---------------- bf16 MFMA GEMM: C = A(MxK) @ W(NxK)^T ----------------
#define GBM 128
#define GBK 64
#define EPLD 132   // padded LDS row (elements) for the epilogue tile

template<int DBUF, int EPI>
__global__ __launch_bounds__(256)
void mfma_gemm(const __hip_bfloat16* __restrict__ A, int lda,
               const __hip_bfloat16* __restrict__ W, int ldw,
               int K, int Kslice, int Nw, int flipA,
               const float* __restrict__ aux,
               float* __restrict__ out0,
               __hip_bfloat16* __restrict__ ob1,
               __hip_bfloat16* __restrict__ ob2,
               _Float16* __restrict__ oh)
{
    __shared__ __attribute__((aligned(16))) char smem[DBUF ? 65536 : 33792];
    const int BOFF = DBUF ? 32768 : 16384;
    int t = threadIdx.x;
    int lane = t & 63, wid = t >> 6;
    int wm = wid >> 1, wn = wid & 1;

    // 2D-chunked XCD-aware swizzle (bijective for all our grids).
    int bx, by;
    {
        int gx = gridDim.x, gy = gridDim.y;
        int nwg = gx * gy;
        int orig = blockIdx.y * gx + blockIdx.x;
        int xcd = orig & 7;
        int c = orig >> 3;
        int npx = nwg >> 3;              // blocks per XCD
        int Wc = gx < 8 ? gx : 8;        // region width (tiles)
        int Hc = npx / Wc;               // region height
        int regx = gx / Wc;              // regions across
        int rx = xcd % regx, ry = xcd / regx;
        bx = rx * Wc + (c % Wc);
        by = ry * Hc + (c / Wc);
    }
    int m0 = by * GBM, n0 = bx * GBM;
    int kz = blockIdx.z;
    int k_begin = kz * Kslice;
    int k_end   = (k_begin + Kslice < K) ? (k_begin + Kslice) : K;
    int ktiles  = (k_end - k_begin) / GBK;

    f32x4 acc[4][4];
    #pragma unroll
    for (int i = 0; i < 4; ++i)
        #pragma unroll
        for (int j = 0; j < 4; ++j)
            acc[i][j] = (f32x4){0.f, 0.f, 0.f, 0.f};

    int arows[4], brows[4], cbs[4];
    #pragma unroll
    for (int p = 0; p < 4; ++p) {
        int o = p * 4096 + t * 16;
        int l = o ^ (((o >> 7) & 7) << 4);
        int r = l >> 7, cb = l & 127;
        int gr = m0 + r;
        if (flipA) gr = (gr & ~(L_ - 1)) | ((L_ - 1) - (gr & (L_ - 1)));
        arows[p] = gr;
        int wr = n0 + r; if (wr >= Nw) wr = Nw - 1;   // clamp (N=96 case)
        brows[p] = wr;
        cbs[p] = cb;
    }

    #define STAGE(buf, k0)                                                        \
        {                                                                         \
            _Pragma("unroll")                                                     \
            for (int p = 0; p < 4; ++p) {                                         \
                int o = p * 4096 + t * 16;                                        \
                const char* gA = (const char*)(A + (size_t)arows[p] * lda + (k0)) \
                                 + cbs[p];                                        \
                gload_lds16(gA, smem + (buf) * 16384 + o);                        \
                const char* gB = (const char*)(W + (size_t)brows[p] * ldw + (k0)) \
                                 + cbs[p];                                        \
                gload_lds16(gB, smem + BOFF + (buf) * 16384 + o);                 \
            }                                                                     \
        }

    auto compute_tile = [&](int pbv) {
        char* bA = smem + pbv * 16384;
        char* bB = smem + BOFF + pbv * 16384;
        #pragma unroll
        for (int ks = 0; ks < 2; ++ks) {
            bf16x8 af[4], bfv[4];
            #pragma unroll
            for (int f = 0; f < 4; ++f) {
                int rowA = wm * 64 + f * 16 + (lane & 15);
                int lA = rowA * 128 + ks * 64 + ((lane >> 4) << 4);
                int pA = lA ^ ((rowA & 7) << 4);
                af[f] = *(const bf16x8*)(bA + pA);
                int rowB = wn * 64 + f * 16 + (lane & 15);
                int lB = rowB * 128 + ks * 64 + ((lane >> 4) << 4);
                int pB = lB ^ ((rowB & 7) << 4);
                bfv[f] = *(const bf16x8*)(bB + pB);
            }
            #pragma unroll
            for (int i = 0; i < 4; ++i)
                #pragma unroll
                for (int j = 0; j < 4; ++j)
                    acc[i][j] = __builtin_amdgcn_mfma_f32_16x16x32_bf16(
                        af[i], bfv[j], acc[i][j], 0, 0, 0);
        }
    };

    if (DBUF) {
        STAGE(0, k_begin);
        int pb = 0;
        for (int kt = 0; kt < ktiles; ++kt) {
            if (kt + 1 < ktiles) {
                STAGE(pb ^ 1, k_begin + (kt + 1) * GBK);
                asm volatile("s_waitcnt vmcnt(8)" ::: "memory");
            } else {
                asm volatile("s_waitcnt vmcnt(0)" ::: "memory");
            }
            __builtin_amdgcn_s_barrier();
            compute_tile(pb);
            __builtin_amdgcn_s_barrier();
            pb ^= 1;
        }
    } else {
        for (int kt = 0; kt < ktiles; ++kt) {
            STAGE(0, k_begin + kt * GBK);
            __syncthreads();
            compute_tile(0);
            __syncthreads();
        }
    }
    #undef STAGE

    // Epilogue. C/D layout: col = lane&15, row = (lane>>4)*4 + reg.
    if (EPI == 0) {
        bool zh = (n0 >= DI_);
        __hip_bfloat16* tile = (__hip_bfloat16*)smem;
        __syncthreads();
        #pragma unroll
        for (int i = 0; i < 4; ++i)
            #pragma unroll
            for (int j = 0; j < 4; ++j) {
                int col = wn * 64 + j * 16 + (lane & 15);
                #pragma unroll
                for (int r = 0; r < 4; ++r) {
                    int row = wm * 64 + i * 16 + ((lane >> 4) << 2) + r;
                    float v = acc[i][j][r];
                    if (zh) v = v / (1.f + __expf(-v));
                    tile[row * EPLD + col] = __float2bfloat16(v);
                }
            }
        __syncthreads();
        __hip_bfloat16* dst = zh ? ob2 : ob1;
        int nb = zh ? n0 - DI_ : n0;
        #pragma unroll
        for (int it = 0; it < 8; ++it) {
            int row = it * 16 + (t >> 4);
            int c8 = (t & 15) * 8;
            bf16x8 vv = *(const bf16x8*)&tile[row * EPLD + c8];
            *(bf16x8*)(dst + (size_t)(m0 + row) * DI_ + nb + c8) = vv;
        }
    } else if (EPI == 4) {
        _Float16* tile = (_Float16*)smem;
        float bias_j[4];
        #pragma unroll
        for (int j = 0; j < 4; ++j)
            bias_j[j] = aux[n0 + wn * 64 + j * 16 + (lane & 15)];
        __syncthreads();
        #pragma unroll
        for (int i = 0; i < 4; ++i)
            #pragma unroll
            for (int j = 0; j < 4; ++j) {
                int col = wn * 64 + j * 16 + (lane & 15);
                #pragma unroll
                for (int r = 0; r < 4; ++r) {
                    int row = wm * 64 + i * 16 + ((lane >> 4) << 2) + r;
                    float v = acc[i][j][r] + bias_j[j];
                    float sp = fmaxf(v, 0.f) + __logf(1.f + __expf(-fabsf(v)));
                    tile[row * EPLD + col] = (_Float16)sp;
                }
            }
        __syncthreads();
        #pragma unroll
        for (int it = 0; it < 8; ++it) {
            int row = it * 16 + (t >> 4);
            int c8 = (t & 15) * 8;
            bf16x8 vv = *(const bf16x8*)&tile[row * EPLD + c8];
            *(bf16x8*)(oh + (size_t)(m0 + row) * DI_ + n0 + c8) = vv;
        }
    } else if (EPI == 3) {
        // xproj split-K partial -> bf16, LDS-coalesced (padded ldc=128)
        __hip_bfloat16* tile = (__hip_bfloat16*)smem;
        __syncthreads();
        #pragma unroll
        for (int i = 0; i < 4; ++i)
            #pragma unroll
            for (int j = 0; j < 4; ++j) {
                int col = wn * 64 + j * 16 + (lane & 15);
                #pragma unroll
                for (int r = 0; r < 4; ++r) {
                    int row = wm * 64 + i * 16 + ((lane >> 4) << 2) + r;
                    tile[row * EPLD + col] = __float2bfloat16(acc[i][j][r]);
                }
            }
        __syncthreads();
        #pragma unroll
        for (int it = 0; it < 8; ++it) {
            int row = it * 16 + (t >> 4);
            int c8 = (t & 15) * 8;
            bf16x8 vv = *(const bf16x8*)&tile[row * EPLD + c8];
            *(bf16x8*)(ob1 + ((size_t)kz * (B_ * L_) + m0 + row) * 128 + n0 + c8) = vv;
        }
    } else { // EPI == 1: out_proj split-K bf16 partial [kz][M][DM]
        #pragma unroll
        for (int i = 0; i < 4; ++i) {
            #pragma unroll
            for (int j = 0; j < 4; ++j) {
                f32x4 a4 = acc[i][j];
                int gn = n0 + wn * 64 + j * 16 + (lane & 15);
                #pragma unroll
                for (int r = 0; r < 4; ++r) {
                    int gm = m0 + wm * 64 + i * 16 + ((lane >> 4) << 2) + r;
                    ob1[((size_t)kz * (B_ * L_) + gm) * DM_ + gn] =
                        __float2bfloat16(a4[r]);
                }
            }
        }
    }
}

// ---------------- out_proj split-K(x4) reduce + residual ----------------
__global__ __launch_bounds__(256)
void out_reduce(const __hip_bfloat16* __restrict__ pout,
                const float* __restrict__ x,
                float* __restrict__ out)
{
    const size_t BLDM = (size_t)B_ * L_ * DM_;
    size_t i = ((size_t)blockIdx.x * 256 + threadIdx.x) * 8;
    bf16x8 p0 = *(const bf16x8*)(pout + i);
    bf16x8 p1 = *(const bf16x8*)(pout + BLDM + i);
    bf16x8 p2 = *(const bf16x8*)(pout + 2 * BLDM + i);
    bf16x8 p3 = *(const bf16x8*)(pout + 3 * BLDM + i);
    float4 x0 = *(const float4*)(x + i);
    float4 x1 = *(const float4*)(x + i + 4);
    float o[8];
    #pragma unroll
    for (int k = 0; k < 8; ++k)
        o[k] = 0.5f * ((bf2f(p0[k]) + bf2f(p1[k])) + (bf2f(p2[k]) + bf2f(p3[k])));
    float4 o0, o1;
    o0.x = x0.x + o[0]; o0.y = x0.y + o[1]; o0.z = x0.z + o[2]; o0.w = x0.w + o[3];
    o1.x = x1.x + o[4]; o1.y = x1.y + o[5]; o1.z = x1.z + o[6]; o1.w = x1.w + o[7];
    *(float4*)(out + i) = o0;
    *(float4*)(out + i + 4) = o1;
}

// ---------------- xproj split-K reduce (bf16 partials, vectorized) ---------
__global__ __launch_bounds__(256)
void xproj_reduce(const __hip_bfloat16* __restrict__ pbufB,
                  float* __restrict__ dbcF,
                  __hip_bfloat16* __restrict__ dbcB)
{
    int idx = blockIdx.x * 256 + threadIdx.x;   // (B*L) * 16 threads-of-8
    int m = idx >> 4;
    int n8 = (idx & 15) * 8;
    float sum[8] = {0.f,0.f,0.f,0.f,0.f,0.f,0.f,0.f};
    #pragma unroll
    for (int k = 0; k < KS_; ++k) {
        bf16x8 v = *(const bf16x8*)&pbufB[((size_t)k * (B_ * L_) + m) * 128 + n8];
        #pragma unroll
        for (int i = 0; i < 8; ++i) sum[i] += bf2f(v[i]);
    }
    #pragma unroll
    for (int i = 0; i < 8; ++i) {
        int n = n8 + i;
        if (n < NDBC_) dbcF[(size_t)m * NDBC_ + n] = sum[i];
    }
    if (n8 < DTR_) {
        short ob[8];
        #pragma unroll
        for (int i = 0; i < 8; ++i) {
            union { __hip_bfloat16 h; short s; } cv;
            cv.h = __float2bfloat16(sum[i]);
            ob[i] = cv.s;
        }
        *(bf16x8*)&dbcB[(size_t)m * DTR_ + n8] = *(const bf16x8*)ob;
    }
}

// ---------------- Causal depthwise conv (width 4) + bias + SiLU ----------------
__global__ __launch_bounds__(256)
void conv_kernel(const __hip_bfloat16* __restrict__ u0,
                 const float* __restrict__ cw,
                 const float* __restrict__ cb,
                 __hip_bfloat16* __restrict__ u)
{
    int e = (blockIdx.x * 256 + threadIdx.x) * 8;   // over B*L*DI
    int d = e & (DI_ - 1);
    int row = e >> 11;              // b*L + l
    int l = row & (L_ - 1);
    size_t base = (size_t)row * DI_ + d;
    float acc[8];
    float4 wv[8];
    #pragma unroll
    for (int i = 0; i < 8; ++i) {
        acc[i] = cb[d + i];
        wv[i]  = ((const float4*)cw)[d + i];
    }
    bf16x8 v;
    if (l >= 3) {
        v = *(const bf16x8*)(u0 + base - 3 * (size_t)DI_);
        #pragma unroll
        for (int i = 0; i < 8; ++i) acc[i] = fmaf(wv[i].x, bf2f(v[i]), acc[i]);
    }
    if (l >= 2) {
        v = *(const bf16x8*)(u0 + base - 2 * (size_t)DI_);
        #pragma unroll
        for (int i = 0; i < 8; ++i) acc[i] = fmaf(wv[i].y, bf2f(v[i]), acc[i]);
    }
    if (l >= 1) {
        v = *(const bf16x8*)(u0 + base - 1 * (size_t)DI_);
        #pragma unroll
        for (int i = 0; i < 8; ++i) acc[i] = fmaf(wv[i].z, bf2f(v[i]), acc[i]);
    }
    v = *(const bf16x8*)(u0 + base);
    #pragma unroll
    for (int i = 0; i < 8; ++i) acc[i] = fmaf(wv[i].w, bf2f(v[i]), acc[i]);
    short ob[8];
    #pragma unroll
    for (int i = 0; i < 8; ++i) {
        float sv = acc[i] / (1.f + __expf(-acc[i]));   // silu
        union { __hip_bfloat16 h; short s; } cvu;
        cvu.h = __float2bfloat16(sv);
        ob[i] = cvu.s;
    }
    *(bf16x8*)(u + base) = *(const bf16x8*)ob;
}

// ---------------- Segmented selective scan: thread-per-channel ----------------
// A_log is log(1..16) tiled -> A[d][s] = -(s+1): fast multiply-chain path.
// T14 async-STAGE: chunk-1 global loads into registers during chunk-0 compute.
// hseg stored as bf16 (fp32 register math; ~0.5% storage rounding).

// Pass 1: per-segment local scan from h=0; store final h + sum(dt).
__global__ __launch_bounds__(256)
void scan_part1(const _Float16* __restrict__ dtb,
                const __hip_bfloat16* __restrict__ ub,
                const float* __restrict__ dbcF,
                const float* __restrict__ A_log,
                __hip_bfloat16* __restrict__ hseg,  // [b][seg][s][DI] bf16
                float* __restrict__ dtsum)          // [b][seg][DI]
{
    __shared__ _Float16 sdt[CT][256];
    __shared__ __hip_bfloat16 su[CT][256];
    __shared__ float sB[CT][DS_];
    int t = threadIdx.x;
    int d0 = blockIdx.x * 256, seg = blockIdx.y, b = blockIdx.z;
    int d = d0 + t;
    size_t rowbase = (size_t)b * L_ + seg * SEGLEN;

    int rw0 = t >> 5, rw1 = 8 + (t >> 5);
    int c8 = (t & 31) * 8;
    int bl = t >> 4, bs = t & 15;

    bf16x8 vdt0 = *(const bf16x8*)&dtb[(rowbase + rw0) * DI_ + d0 + c8];
    bf16x8 vdt1 = *(const bf16x8*)&dtb[(rowbase + rw1) * DI_ + d0 + c8];
    bf16x8 vu0  = *(const bf16x8*)&ub [(rowbase + rw0) * DI_ + d0 + c8];
    bf16x8 vu1  = *(const bf16x8*)&ub [(rowbase + rw1) * DI_ + d0 + c8];
    float  vB   = dbcF[(rowbase + bl) * NDBC_ + DTR_ + bs];

    float A2[DS_], h[DS_];
    bool fastA = true;
    #pragma unroll
    for (int s = 0; s < DS_; ++s) {
        float a = __expf(A_log[d * DS_ + s]);
        A2[s] = -a * LOG2E;
        fastA = fastA && (fabsf(a - (float)(s + 1)) < 1e-3f);
        h[s] = 0.f;
    }
    float dts = 0.f;

    auto store_lds = [&]() {
        *(bf16x8*)&sdt[rw0][c8] = vdt0;
        *(bf16x8*)&sdt[rw1][c8] = vdt1;
        *(bf16x8*)&su[rw0][c8]  = vu0;
        *(bf16x8*)&su[rw1][c8]  = vu1;
        sB[bl][bs] = vB;
    };
    auto compute_chunk = [&]() {
        if (fastA) {
            for (int l = 0; l < CT; ++l) {
                float dtv = (float)sdt[l][t];
                float du  = dtv * __bfloat162float(su[l][t]);
                dts += dtv;
                float g = exp2f(-dtv * LOG2E);
                float r = 1.f;
                #pragma unroll
                for (int s = 0; s < DS_; ++s) {
                    r *= g;
                    h[s] = r * h[s] + du * sB[l][s];
                }
            }
        } else {
            for (int l = 0; l < CT; ++l) {
                float dtv = (float)sdt[l][t];
                float du  = dtv * __bfloat162float(su[l][t]);
                dts += dtv;
                #pragma unroll
                for (int s = 0; s < DS_; ++s)
                    h[s] = exp2f(dtv * A2[s]) * h[s] + du * sB[l][s];
            }
        }
    };

    store_lds();
    __syncthreads();

    vdt0 = *(const bf16x8*)&dtb[(rowbase + CT + rw0) * DI_ + d0 + c8];
    vdt1 = *(const bf16x8*)&dtb[(rowbase + CT + rw1) * DI_ + d0 + c8];
    vu0  = *(const bf16x8*)&ub [(rowbase + CT + rw0) * DI_ + d0 + c8];
    vu1  = *(const bf16x8*)&ub [(rowbase + CT + rw1) * DI_ + d0 + c8];
    vB   = dbcF[(rowbase + CT + bl) * NDBC_ + DTR_ + bs];

    compute_chunk();
    __syncthreads();
    store_lds();
    __syncthreads();
    compute_chunk();

    #pragma unroll
    for (int s = 0; s < DS_; ++s)
        hseg[(((size_t)b * NSEG + seg) * DS_ + s) * DI_ + d] =
            __float2bfloat16(h[s]);
    dtsum[((size_t)b * NSEG + seg) * DI_ + d] = dts;
}

// Pass 2: inter-segment scan with load-ahead prefetch (fp32 register math).
__global__ __launch_bounds__(256)
void seg_scan(__hip_bfloat16* __restrict__ hseg,
              const float* __restrict__ dtsum,
              const float* __restrict__ A_log)
{
    int idx = blockIdx.x * 256 + threadIdx.x;   // b*DI*DS, d fastest
    int d = idx & (DI_ - 1);
    int s = (idx >> 11) & 15;
    int b = idx >> 15;
    float A2 = -__expf(A_log[d * DS_ + s]) * LOG2E;
    float h = 0.f;
    size_t o = (((size_t)b * NSEG + 0) * DS_ + s) * DI_ + d;
    size_t oi = ((size_t)b * NSEG + 0) * DI_ + d;
    float pv = __bfloat162float(hseg[o]), ds = dtsum[oi];
    for (int g = 0; g < NSEG; ++g) {
        float npv = 0.f, nds = 0.f;
        if (g + 1 < NSEG) {
            npv = __bfloat162float(hseg[o + (size_t)DS_ * DI_]);
            nds = dtsum[oi + DI_];
        }
        hseg[o] = __float2bfloat16(h);
        h = exp2f(A2 * ds) * h + pv;
        pv = npv; ds = nds;
        o += (size_t)DS_ * DI_;
        oi += DI_;
    }
}

// Pass 3: re-scan with correct h_in; write y into yb_cat[row][dir*DI+d].
__global__ __launch_bounds__(256)
void scan_part2(const _Float16* __restrict__ dtb,
                const __hip_bfloat16* __restrict__ ub,
                const __hip_bfloat16* __restrict__ zs,
                const float* __restrict__ dbcF,
                const float* __restrict__ A_log,
                const float* __restrict__ Dskip,
                const __hip_bfloat16* __restrict__ hseg,
                __hip_bfloat16* __restrict__ ycat,
                int dir)
{
    __shared__ _Float16 sdt[CT][256];
    __shared__ __hip_bfloat16 su[CT][256], sz[CT][256], sy[CT][256];
    __shared__ float sB[CT][DS_], sC[CT][DS_];
    int t = threadIdx.x;
    int d0 = blockIdx.x * 256, seg = blockIdx.y, b = blockIdx.z;
    int d = d0 + t;
    size_t rowbase = (size_t)b * L_ + seg * SEGLEN;
    int ycol0 = dir * DI_ + d0;

    int rw0 = t >> 5, rw1 = 8 + (t >> 5);
    int c8 = (t & 31) * 8;
    int bl = t >> 4, bs = t & 15;

    bf16x8 vdt0 = *(const bf16x8*)&dtb[(rowbase + rw0) * DI_ + d0 + c8];
    bf16x8 vdt1 = *(const bf16x8*)&dtb[(rowbase + rw1) * DI_ + d0 + c8];
    bf16x8 vu0  = *(const bf16x8*)&ub [(rowbase + rw0) * DI_ + d0 + c8];
    bf16x8 vu1  = *(const bf16x8*)&ub [(rowbase + rw1) * DI_ + d0 + c8];
    bf16x8 vz0  = *(const bf16x8*)&zs [(rowbase + rw0) * DI_ + d0 + c8];
    bf16x8 vz1  = *(const bf16x8*)&zs [(rowbase + rw1) * DI_ + d0 + c8];
    float  vB   = dbcF[(rowbase + bl) * NDBC_ + DTR_ + bs];
    float  vC   = dbcF[(rowbase + bl) * NDBC_ + DTR_ + DS_ + bs];

    float A2[DS_], h[DS_];
    bool fastA = true;
    #pragma unroll
    for (int s = 0; s < DS_; ++s) {
        float a = __expf(A_log[d * DS_ + s]);
        A2[s] = -a * LOG2E;
        fastA = fastA && (fabsf(a - (float)(s + 1)) < 1e-3f);
        h[s] = __bfloat162float(
            hseg[(((size_t)b * NSEG + seg) * DS_ + s) * DI_ + d]);
    }
    float Dd = Dskip[d];

    auto store_lds = [&]() {
        *(bf16x8*)&sdt[rw0][c8] = vdt0;
        *(bf16x8*)&sdt[rw1][c8] = vdt1;
        *(bf16x8*)&su[rw0][c8]  = vu0;
        *(bf16x8*)&su[rw1][c8]  = vu1;
        *(bf16x8*)&sz[rw0][c8]  = vz0;
        *(bf16x8*)&sz[rw1][c8]  = vz1;
        sB[bl][bs] = vB;
        sC[bl][bs] = vC;
    };
    auto compute_chunk = [&]() {
        if (fastA) {
            for (int l = 0; l < CT; ++l) {
                float dtv = (float)sdt[l][t];
                float uu  = __bfloat162float(su[l][t]);
                float du  = dtv * uu;
                float g = exp2f(-dtv * LOG2E);
                float r = 1.f;
                float y = 0.f;
                #pragma unroll
                for (int s = 0; s < DS_; ++s) {
                    r *= g;
                    h[s] = r * h[s] + du * sB[l][s];
                    y = fmaf(h[s], sC[l][s], y);
                }
                y = (y + Dd * uu) * __bfloat162float(sz[l][t]);
                sy[l][t] = __float2bfloat16(y);
            }
        } else {
            for (int l = 0; l < CT; ++l) {
                float dtv = (float)sdt[l][t];
                float uu  = __bfloat162float(su[l][t]);
                float du  = dtv * uu;
                float y = 0.f;
                #pragma unroll
                for (int s = 0; s < DS_; ++s) {
                    h[s] = exp2f(dtv * A2[s]) * h[s] + du * sB[l][s];
                    y = fmaf(h[s], sC[l][s], y);
                }
                y = (y + Dd * uu) * __bfloat162float(sz[l][t]);
                sy[l][t] = __float2bfloat16(y);
            }
        }
    };
    auto store_y = [&](int c) {
        #pragma unroll
        for (int p2 = 0; p2 < 2; ++p2) {
            int e = t + p2 * 256;
            int row = e >> 5, cc = (e & 31) * 8;
            int lg = seg * SEGLEN + c * CT + row;
            int lw = dir ? (L_ - 1 - lg) : lg;
            *(bf16x8*)&ycat[((size_t)b * L_ + lw) * NXZ_ + ycol0 + cc] =
                *(const bf16x8*)&sy[row][cc];
        }
    };

    store_lds();
    __syncthreads();

    vdt0 = *(const bf16x8*)&dtb[(rowbase + CT + rw0) * DI_ + d0 + c8];
    vdt1 = *(const bf16x8*)&dtb[(rowbase + CT + rw1) * DI_ + d0 + c8];
    vu0  = *(const bf16x8*)&ub [(rowbase + CT + rw0) * DI_ + d0 + c8];
    vu1  = *(const bf16x8*)&ub [(rowbase + CT + rw1) * DI_ + d0 + c8];
    vz0  = *(const bf16x8*)&zs [(rowbase + CT + rw0) * DI_ + d0 + c8];
    vz1  = *(const bf16x8*)&zs [(rowbase + CT + rw1) * DI_ + d0 + c8];
    vB   = dbcF[(rowbase + CT + bl) * NDBC_ + DTR_ + bs];
    vC   = dbcF[(rowbase + CT + bl) * NDBC_ + DTR_ + DS_ + bs];

    compute_chunk();            // chunk 0 -> sy
    __syncthreads();
    store_y(0);
    store_lds();                // chunk 1 -> LDS
    __syncthreads();
    compute_chunk();            // chunk 1 -> sy
    __syncthreads();
    store_y(1);
}

extern "C" void kernel_launch(void* const* d_in, const int* in_sizes, int n_in,
                              void* d_out, int out_size, void* d_ws, size_t ws_size,
                              hipStream_t stream)
{
    (void)in_sizes; (void)n_in; (void)out_size; (void)ws_size;
    const float* x     = (const float*)d_in[0];
    const float* gamma = (const float*)d_in[1];
    const float* beta  = (const float*)d_in[2];
    float* out = (float*)d_out;

    const size_t BLDI = (size_t)B_ * L_ * DI_;      // 8,388,608

    // workspace (~131 MB); u0/pbufB/dtF time-share shreg per dir;
    // out_proj bf16 partials (KO=4 -> 33.6 MB) span hsegB+shreg+lnb at the
    // end (all dead before out_proj; ycat/x untouched).
    float* ws    = (float*)d_ws;
    float* dbcF  = ws;                               // 1.57 MB
    float* dtsum = dbcF + (size_t)B_ * L_ * NDBC_;   // 1.05 MB
    __hip_bfloat16* hsegB = (__hip_bfloat16*)(dtsum + (size_t)B_ * NSEG * DI_); // 8.39 MB
    float* shreg = (float*)(hsegB + (size_t)B_ * NSEG * DI_ * DS_);  // 16.78 MB
    __hip_bfloat16* lnb  = (__hip_bfloat16*)(shreg + BLDI / 2);      // 8.39 MB
    __hip_bfloat16* ub   = lnb + (size_t)B_ * L_ * DM_;   // 16.78
    __hip_bfloat16* zs   = ub + BLDI;                     // 16.78
    __hip_bfloat16* ycat = zs + BLDI;                     // 33.55 (both dirs, K-cat)
    __hip_bfloat16* win  = ycat + (size_t)B_ * L_ * NXZ_; // 16.78 (both dirs)
    __hip_bfloat16* wocat= win + (size_t)2 * NXZ_ * DM_;  // 8.39  ([DM][2*DI])
    __hip_bfloat16* xpw  = wocat + (size_t)DM_ * NXZ_;    // 0.79 (both dirs)
    __hip_bfloat16* dtw  = xpw + (size_t)2 * NDBC_ * DI_; // 0.53 (both dirs)
    __hip_bfloat16* dbcB = dtw + (size_t)2 * DI_ * DTR_;  // 0.52 (per-dir reuse)
    // aliases of shreg (sequential lifetimes within each dir):
    __hip_bfloat16* u0b   = (__hip_bfloat16*)shreg;  // in_proj -> conv
    __hip_bfloat16* pbufB = (__hip_bfloat16*)shreg;  // xproj bf16 partials (8.4MB)
    _Float16*       dtF   = (_Float16*)shreg;        // dt gemm -> scans
    __hip_bfloat16* pout  = hsegB;                   // out bf16 partials (4 slices,
                                                     // spans hsegB+shreg+lnb)

    dim3 blk(256);

    // all weights -> bf16 in a single dispatch
    cvt_all<<<12928, blk, 0, stream>>>(
        (const float*)d_in[3],  (const float*)d_in[12],
        (const float*)d_in[11], (const float*)d_in[20],
        (const float*)d_in[6],  (const float*)d_in[15],
        (const float*)d_in[7],  (const float*)d_in[16],
        win, wocat, xpw, dtw);

    ln_kernel<<<B_ * L_, blk, 0, stream>>>(x, gamma, beta, lnb);

    for (int dir = 0; dir < 2; ++dir) {
        int base = 3 + dir * 9;
        const float* conv_w  = (const float*)d_in[base + 1];
        const float* conv_b  = (const float*)d_in[base + 2];
        const float* dt_b    = (const float*)d_in[base + 5];
        const float* A_log   = (const float*)d_in[base + 6];
        const float* Dsk     = (const float*)d_in[base + 7];

        // in_proj: [u0b | silu(z)->zs] = ln(flip?) @ in_w^T  (dbuf+counted vmcnt)
        mfma_gemm<1, 0><<<dim3(NXZ_ / GBM, (B_ * L_) / GBM), blk, 0, stream>>>(
            lnb, DM_, win + (size_t)dir * NXZ_ * DM_, DM_,
            DM_, DM_, NXZ_, dir, nullptr, nullptr, u0b, zs, nullptr);

        conv_kernel<<<(B_ * L_ * DI_) / 2048, blk, 0, stream>>>(
            u0b, conv_w, conv_b, ub);

        // xproj: dbc = u @ xproj_w^T (N=96), split-K x8 -> bf16 partials
        mfma_gemm<1, 3><<<dim3(1, (B_ * L_) / GBM, KS_), blk, 0, stream>>>(
            ub, DI_, xpw + (size_t)dir * NDBC_ * DI_, DI_,
            DI_, DI_ / KS_, NDBC_, 0, nullptr, nullptr, pbufB, nullptr, nullptr);
        xproj_reduce<<<(B_ * L_ * 16) / 256, blk, 0, stream>>>(pbufB, dbcF, dbcB);

        // dt = softplus(dbc[:, :64] @ dt_w^T + dt_b) -> fp16 (shreg)
        mfma_gemm<0, 4><<<dim3(DI_ / GBM, (B_ * L_) / GBM), blk, 0, stream>>>(
            dbcB, DTR_, dtw + (size_t)dir * DI_ * DTR_, DTR_,
            DTR_, DTR_, DI_, 0, dt_b, nullptr, nullptr, nullptr, dtF);

        // segmented scan (thread-per-channel, states in registers)
        scan_part1<<<dim3(DI_ / 256, NSEG, B_), blk, 0, stream>>>(
            dtF, ub, dbcF, A_log, hsegB, dtsum);
        seg_scan<<<(B_ * DI_ * DS_) / 256, blk, 0, stream>>>(hsegB, dtsum, A_log);
        scan_part2<<<dim3(DI_ / 256, NSEG, B_), blk, 0, stream>>>(
            dtF, ub, zs, dbcF, A_log, Dsk, hsegB, ycat, dir);
    }

    // merged out_proj: split-K x4 (dbuf, 1024 blocks) -> bf16 partials, then
    // out = x + 0.5*(p0+p1+p2+p3)
    mfma_gemm<1, 1><<<dim3(DM_ / GBM, (B_ * L_) / GBM, KO_), blk, 0, stream>>>(
        ycat, NXZ_, wocat, NXZ_, NXZ_, NXZ_ / KO_, DM_, 0,
        nullptr, nullptr, pout, nullptr, nullptr);
    out_reduce<<<(B_ * L_ * DM_) / 2048, blk, 0, stream>>>(pout, x, out);
}

// Round 24
// 372.677 us; speedup vs baseline: 1.0087x; 1.0087x over previous
//
#include <hip/hip_runtime.h>
#include <hip/hip_bf16.h>
#include <math.h>

// Problem constants
#define B_    2
#define L_    2048
#define DM_   1024      // d_model
#define DI_   2048      // d_inner
#define DS_   16        // d_state
#define DTR_  64        // dt_rank
#define NXZ_  4096      // 2*d_inner
#define NDBC_ 96        // dt_rank + 2*d_state

#define NSEG   64
#define SEGLEN 32
#define CT     16       // timesteps staged per chunk
#define KS_    8        // xproj split-K factor
#define KO_    2        // out_proj split-K factor (A/B-confirmed best)

#define LOG2E 1.4426950408889634f

typedef __attribute__((ext_vector_type(8))) short bf16x8;
typedef __attribute__((ext_vector_type(4))) float f32x4;

__device__ __forceinline__ void gload_lds16(const void* g, void* l) {
    __builtin_amdgcn_global_load_lds(
        (const __attribute__((address_space(1))) void*)g,
        (__attribute__((address_space(3))) void*)l,
        16, 0, 0);
}

__device__ __forceinline__ float bf2f(short s) {
    union { unsigned u; float f; } x;
    x.u = ((unsigned)(unsigned short)s) << 16;
    return x.f;
}

// ---------------- LayerNorm (one block per row) -> bf16 out ----------------
__global__ __launch_bounds__(256)
void ln_kernel(const float* __restrict__ x,
               const float* __restrict__ gamma,
               const float* __restrict__ beta,
               __hip_bfloat16* __restrict__ out)
{
    int row = blockIdx.x;
    int t = threadIdx.x;
    const float* xr = x + (size_t)row * DM_;
    float4 v = ((const float4*)xr)[t];
    float s  = v.x + v.y + v.z + v.w;
    float ss = v.x*v.x + v.y*v.y + v.z*v.z + v.w*v.w;
    #pragma unroll
    for (int m = 1; m < 64; m <<= 1) {
        s  += __shfl_xor(s,  m, 64);
        ss += __shfl_xor(ss, m, 64);
    }
    __shared__ float as_[4], ass_[4];
    int w = t >> 6;
    if ((t & 63) == 0) { as_[w] = s; ass_[w] = ss; }
    __syncthreads();
    s  = as_[0] + as_[1] + as_[2] + as_[3];
    ss = ass_[0] + ass_[1] + ass_[2] + ass_[3];
    float mu  = s * (1.0f / DM_);
    float var = ss * (1.0f / DM_) - mu * mu;
    float inv = rsqrtf(var + 1e-5f);
    float4 g  = ((const float4*)gamma)[t];
    float4 bt = ((const float4*)beta)[t];
    __hip_bfloat16 ob[4];
    ob[0] = __float2bfloat16((v.x - mu) * inv * g.x + bt.x);
    ob[1] = __float2bfloat16((v.y - mu) * inv * g.y + bt.y);
    ob[2] = __float2bfloat16((v.z - mu) * inv * g.z + bt.z);
    ob[3] = __float2bfloat16((v.w - mu) * inv * g.w + bt.w);
    ((ushort4*)(out + (size_t)row * DM_))[t] = *(const ushort4*)ob;
}

// ---------------- merged weight convert (all 8 weights, both dirs) ---------
__global__ __launch_bounds__(256)
void cvt_all(const float* __restrict__ inw_f, const float* __restrict__ inw_b,
             const float* __restrict__ ow_f,  const float* __restrict__ ow_b,
             const float* __restrict__ xp_f,  const float* __restrict__ xp_b,
             const float* __restrict__ dw_f,  const float* __restrict__ dw_b,
             __hip_bfloat16* __restrict__ win,
             __hip_bfloat16* __restrict__ wocat,
             __hip_bfloat16* __restrict__ xpw,
             __hip_bfloat16* __restrict__ dtw)
{
    const int N_WIN = 2 * NXZ_ * DM_;
    const int N_WO  = DM_ * NXZ_;
    const int N_XP  = 2 * NDBC_ * DI_;
    int i = (blockIdx.x * 256 + threadIdx.x) * 4;
    const float* s;
    __hip_bfloat16* dst;
    int dj;
    if (i < N_WIN) {
        int half = NXZ_ * DM_;
        s = (i < half) ? inw_f + i : inw_b + (i - half);
        dst = win; dj = i;
    } else if (i < N_WIN + N_WO) {
        int jj = i - N_WIN;
        int n = jj >> 12, c = jj & 4095;
        int dir = c >> 11, k = c & 2047;
        s = (dir ? ow_b : ow_f) + (size_t)n * DI_ + k;
        dst = wocat; dj = jj;
    } else if (i < N_WIN + N_WO + N_XP) {
        int jj = i - N_WIN - N_WO;
        int half = NDBC_ * DI_;
        s = (jj < half) ? xp_f + jj : xp_b + (jj - half);
        dst = xpw; dj = jj;
    } else {
        int jj = i - N_WIN - N_WO - N_XP;
        int half = DI_ * DTR_;
        s = (jj < half) ? dw_f + jj : dw_b + (jj - half);
        dst = dtw; dj = jj;
    }
    float4 v = *(const float4*)s;
    __hip_bfloat16 ob[4];
    ob[0] = __float2bfloat16(v.x);
    ob[1] = __float2bfloat16(v.y);
    ob[2] = __float2bfloat16(v.z);
    ob[3] = __float2bfloat16(v.w);
    *(ushort4*)(dst + dj) = *(const ushort4*)ob;
}

// ---------------- bf16 MFMA GEMM: C = A(MxK) @ W(NxK)^T ----------------
#define GBM 128
#define GBK 64
#define EPLD 132   // padded LDS row (elements) for the epilogue tile

template<int DBUF, int EPI>
__global__ __launch_bounds__(256)
void mfma_gemm(const __hip_bfloat16* __restrict__ A, int lda,
               const __hip_bfloat16* __restrict__ W, int ldw,
               int K, int Kslice, int Nw, int flipA,
               const float* __restrict__ aux,
               float* __restrict__ out0,
               __hip_bfloat16* __restrict__ ob1,
               __hip_bfloat16* __restrict__ ob2,
               _Float16* __restrict__ oh)
{
    __shared__ __attribute__((aligned(16))) char smem[DBUF ? 65536 : 33792];
    const int BOFF = DBUF ? 32768 : 16384;
    int t = threadIdx.x;
    int lane = t & 63, wid = t >> 6;
    int wm = wid >> 1, wn = wid & 1;

    // 2D-chunked XCD-aware swizzle (bijective for all our grids).
    int bx, by;
    {
        int gx = gridDim.x, gy = gridDim.y;
        int nwg = gx * gy;
        int orig = blockIdx.y * gx + blockIdx.x;
        int xcd = orig & 7;
        int c = orig >> 3;
        int npx = nwg >> 3;              // blocks per XCD
        int Wc = gx < 8 ? gx : 8;        // region width (tiles)
        int Hc = npx / Wc;               // region height
        int regx = gx / Wc;              // regions across
        int rx = xcd % regx, ry = xcd / regx;
        bx = rx * Wc + (c % Wc);
        by = ry * Hc + (c / Wc);
    }
    int m0 = by * GBM, n0 = bx * GBM;
    int kz = blockIdx.z;
    int k_begin = kz * Kslice;
    int k_end   = (k_begin + Kslice < K) ? (k_begin + Kslice) : K;
    int ktiles  = (k_end - k_begin) / GBK;

    f32x4 acc[4][4];
    #pragma unroll
    for (int i = 0; i < 4; ++i)
        #pragma unroll
        for (int j = 0; j < 4; ++j)
            acc[i][j] = (f32x4){0.f, 0.f, 0.f, 0.f};

    int arows[4], brows[4], cbs[4];
    #pragma unroll
    for (int p = 0; p < 4; ++p) {
        int o = p * 4096 + t * 16;
        int l = o ^ (((o >> 7) & 7) << 4);
        int r = l >> 7, cb = l & 127;
        int gr = m0 + r;
        if (flipA) gr = (gr & ~(L_ - 1)) | ((L_ - 1) - (gr & (L_ - 1)));
        arows[p] = gr;
        int wr = n0 + r; if (wr >= Nw) wr = Nw - 1;   // clamp (N=96 case)
        brows[p] = wr;
        cbs[p] = cb;
    }

    #define STAGE(buf, k0)                                                        \
        {                                                                         \
            _Pragma("unroll")                                                     \
            for (int p = 0; p < 4; ++p) {                                         \
                int o = p * 4096 + t * 16;                                        \
                const char* gA = (const char*)(A + (size_t)arows[p] * lda + (k0)) \
                                 + cbs[p];                                        \
                gload_lds16(gA, smem + (buf) * 16384 + o);                        \
                const char* gB = (const char*)(W + (size_t)brows[p] * ldw + (k0)) \
                                 + cbs[p];                                        \
                gload_lds16(gB, smem + BOFF + (buf) * 16384 + o);                 \
            }                                                                     \
        }

    auto compute_tile = [&](int pbv) {
        char* bA = smem + pbv * 16384;
        char* bB = smem + BOFF + pbv * 16384;
        #pragma unroll
        for (int ks = 0; ks < 2; ++ks) {
            bf16x8 af[4], bfv[4];
            #pragma unroll
            for (int f = 0; f < 4; ++f) {
                int rowA = wm * 64 + f * 16 + (lane & 15);
                int lA = rowA * 128 + ks * 64 + ((lane >> 4) << 4);
                int pA = lA ^ ((rowA & 7) << 4);
                af[f] = *(const bf16x8*)(bA + pA);
                int rowB = wn * 64 + f * 16 + (lane & 15);
                int lB = rowB * 128 + ks * 64 + ((lane >> 4) << 4);
                int pB = lB ^ ((rowB & 7) << 4);
                bfv[f] = *(const bf16x8*)(bB + pB);
            }
            #pragma unroll
            for (int i = 0; i < 4; ++i)
                #pragma unroll
                for (int j = 0; j < 4; ++j)
                    acc[i][j] = __builtin_amdgcn_mfma_f32_16x16x32_bf16(
                        af[i], bfv[j], acc[i][j], 0, 0, 0);
        }
    };

    if (DBUF) {
        STAGE(0, k_begin);
        int pb = 0;
        for (int kt = 0; kt < ktiles; ++kt) {
            if (kt + 1 < ktiles) {
                STAGE(pb ^ 1, k_begin + (kt + 1) * GBK);
                asm volatile("s_waitcnt vmcnt(8)" ::: "memory");
            } else {
                asm volatile("s_waitcnt vmcnt(0)" ::: "memory");
            }
            __builtin_amdgcn_s_barrier();
            compute_tile(pb);
            __builtin_amdgcn_s_barrier();
            pb ^= 1;
        }
    } else {
        for (int kt = 0; kt < ktiles; ++kt) {
            STAGE(0, k_begin + kt * GBK);
            __syncthreads();
            compute_tile(0);
            __syncthreads();
        }
    }
    #undef STAGE

    // Epilogue. C/D layout: col = lane&15, row = (lane>>4)*4 + reg.
    if (EPI == 0) {
        bool zh = (n0 >= DI_);
        __hip_bfloat16* tile = (__hip_bfloat16*)smem;
        __syncthreads();
        #pragma unroll
        for (int i = 0; i < 4; ++i)
            #pragma unroll
            for (int j = 0; j < 4; ++j) {
                int col = wn * 64 + j * 16 + (lane & 15);
                #pragma unroll
                for (int r = 0; r < 4; ++r) {
                    int row = wm * 64 + i * 16 + ((lane >> 4) << 2) + r;
                    float v = acc[i][j][r];
                    if (zh) v = v / (1.f + __expf(-v));
                    tile[row * EPLD + col] = __float2bfloat16(v);
                }
            }
        __syncthreads();
        __hip_bfloat16* dst = zh ? ob2 : ob1;
        int nb = zh ? n0 - DI_ : n0;
        #pragma unroll
        for (int it = 0; it < 8; ++it) {
            int row = it * 16 + (t >> 4);
            int c8 = (t & 15) * 8;
            bf16x8 vv = *(const bf16x8*)&tile[row * EPLD + c8];
            *(bf16x8*)(dst + (size_t)(m0 + row) * DI_ + nb + c8) = vv;
        }
    } else if (EPI == 4) {
        _Float16* tile = (_Float16*)smem;
        float bias_j[4];
        #pragma unroll
        for (int j = 0; j < 4; ++j)
            bias_j[j] = aux[n0 + wn * 64 + j * 16 + (lane & 15)];
        __syncthreads();
        #pragma unroll
        for (int i = 0; i < 4; ++i)
            #pragma unroll
            for (int j = 0; j < 4; ++j) {
                int col = wn * 64 + j * 16 + (lane & 15);
                #pragma unroll
                for (int r = 0; r < 4; ++r) {
                    int row = wm * 64 + i * 16 + ((lane >> 4) << 2) + r;
                    float v = acc[i][j][r] + bias_j[j];
                    float sp = fmaxf(v, 0.f) + __logf(1.f + __expf(-fabsf(v)));
                    tile[row * EPLD + col] = (_Float16)sp;
                }
            }
        __syncthreads();
        #pragma unroll
        for (int it = 0; it < 8; ++it) {
            int row = it * 16 + (t >> 4);
            int c8 = (t & 15) * 8;
            bf16x8 vv = *(const bf16x8*)&tile[row * EPLD + c8];
            *(bf16x8*)(oh + (size_t)(m0 + row) * DI_ + n0 + c8) = vv;
        }
    } else if (EPI == 3) {
        // xproj split-K partial -> bf16, LDS-coalesced (padded ldc=128)
        __hip_bfloat16* tile = (__hip_bfloat16*)smem;
        __syncthreads();
        #pragma unroll
        for (int i = 0; i < 4; ++i)
            #pragma unroll
            for (int j = 0; j < 4; ++j) {
                int col = wn * 64 + j * 16 + (lane & 15);
                #pragma unroll
                for (int r = 0; r < 4; ++r) {
                    int row = wm * 64 + i * 16 + ((lane >> 4) << 2) + r;
                    tile[row * EPLD + col] = __float2bfloat16(acc[i][j][r]);
                }
            }
        __syncthreads();
        #pragma unroll
        for (int it = 0; it < 8; ++it) {
            int row = it * 16 + (t >> 4);
            int c8 = (t & 15) * 8;
            bf16x8 vv = *(const bf16x8*)&tile[row * EPLD + c8];
            *(bf16x8*)(ob1 + ((size_t)kz * (B_ * L_) + m0 + row) * 128 + n0 + c8) = vv;
        }
    } else { // EPI == 1: out_proj split-K bf16 partial [kz][M][DM]
        #pragma unroll
        for (int i = 0; i < 4; ++i) {
            #pragma unroll
            for (int j = 0; j < 4; ++j) {
                f32x4 a4 = acc[i][j];
                int gn = n0 + wn * 64 + j * 16 + (lane & 15);
                #pragma unroll
                for (int r = 0; r < 4; ++r) {
                    int gm = m0 + wm * 64 + i * 16 + ((lane >> 4) << 2) + r;
                    ob1[((size_t)kz * (B_ * L_) + gm) * DM_ + gn] =
                        __float2bfloat16(a4[r]);
                }
            }
        }
    }
}

// ---------------- out_proj split-K(x2) reduce + residual ----------------
__global__ __launch_bounds__(256)
void out_reduce(const __hip_bfloat16* __restrict__ pout,
                const float* __restrict__ x,
                float* __restrict__ out)
{
    const size_t BLDM = (size_t)B_ * L_ * DM_;
    size_t i = ((size_t)blockIdx.x * 256 + threadIdx.x) * 8;
    bf16x8 p0 = *(const bf16x8*)(pout + i);
    bf16x8 p1 = *(const bf16x8*)(pout + BLDM + i);
    float4 x0 = *(const float4*)(x + i);
    float4 x1 = *(const float4*)(x + i + 4);
    float4 o0, o1;
    o0.x = x0.x + 0.5f * (bf2f(p0[0]) + bf2f(p1[0]));
    o0.y = x0.y + 0.5f * (bf2f(p0[1]) + bf2f(p1[1]));
    o0.z = x0.z + 0.5f * (bf2f(p0[2]) + bf2f(p1[2]));
    o0.w = x0.w + 0.5f * (bf2f(p0[3]) + bf2f(p1[3]));
    o1.x = x1.x + 0.5f * (bf2f(p0[4]) + bf2f(p1[4]));
    o1.y = x1.y + 0.5f * (bf2f(p0[5]) + bf2f(p1[5]));
    o1.z = x1.z + 0.5f * (bf2f(p0[6]) + bf2f(p1[6]));
    o1.w = x1.w + 0.5f * (bf2f(p0[7]) + bf2f(p1[7]));
    *(float4*)(out + i) = o0;
    *(float4*)(out + i + 4) = o1;
}

// ---------------- xproj split-K reduce (bf16 partials, vectorized) ---------
__global__ __launch_bounds__(256)
void xproj_reduce(const __hip_bfloat16* __restrict__ pbufB,
                  float* __restrict__ dbcF,
                  __hip_bfloat16* __restrict__ dbcB)
{
    int idx = blockIdx.x * 256 + threadIdx.x;   // (B*L) * 16 threads-of-8
    int m = idx >> 4;
    int n8 = (idx & 15) * 8;
    float sum[8] = {0.f,0.f,0.f,0.f,0.f,0.f,0.f,0.f};
    #pragma unroll
    for (int k = 0; k < KS_; ++k) {
        bf16x8 v = *(const bf16x8*)&pbufB[((size_t)k * (B_ * L_) + m) * 128 + n8];
        #pragma unroll
        for (int i = 0; i < 8; ++i) sum[i] += bf2f(v[i]);
    }
    #pragma unroll
    for (int i = 0; i < 8; ++i) {
        int n = n8 + i;
        if (n < NDBC_) dbcF[(size_t)m * NDBC_ + n] = sum[i];
    }
    if (n8 < DTR_) {
        short ob[8];
        #pragma unroll
        for (int i = 0; i < 8; ++i) {
            union { __hip_bfloat16 h; short s; } cv;
            cv.h = __float2bfloat16(sum[i]);
            ob[i] = cv.s;
        }
        *(bf16x8*)&dbcB[(size_t)m * DTR_ + n8] = *(const bf16x8*)ob;
    }
}

// ---------------- Causal depthwise conv (width 4) + bias + SiLU ----------------
__global__ __launch_bounds__(256)
void conv_kernel(const __hip_bfloat16* __restrict__ u0,
                 const float* __restrict__ cw,
                 const float* __restrict__ cb,
                 __hip_bfloat16* __restrict__ u)
{
    int e = (blockIdx.x * 256 + threadIdx.x) * 8;   // over B*L*DI
    int d = e & (DI_ - 1);
    int row = e >> 11;              // b*L + l
    int l = row & (L_ - 1);
    size_t base = (size_t)row * DI_ + d;
    float acc[8];
    float4 wv[8];
    #pragma unroll
    for (int i = 0; i < 8; ++i) {
        acc[i] = cb[d + i];
        wv[i]  = ((const float4*)cw)[d + i];
    }
    bf16x8 v;
    if (l >= 3) {
        v = *(const bf16x8*)(u0 + base - 3 * (size_t)DI_);
        #pragma unroll
        for (int i = 0; i < 8; ++i) acc[i] = fmaf(wv[i].x, bf2f(v[i]), acc[i]);
    }
    if (l >= 2) {
        v = *(const bf16x8*)(u0 + base - 2 * (size_t)DI_);
        #pragma unroll
        for (int i = 0; i < 8; ++i) acc[i] = fmaf(wv[i].y, bf2f(v[i]), acc[i]);
    }
    if (l >= 1) {
        v = *(const bf16x8*)(u0 + base - 1 * (size_t)DI_);
        #pragma unroll
        for (int i = 0; i < 8; ++i) acc[i] = fmaf(wv[i].z, bf2f(v[i]), acc[i]);
    }
    v = *(const bf16x8*)(u0 + base);
    #pragma unroll
    for (int i = 0; i < 8; ++i) acc[i] = fmaf(wv[i].w, bf2f(v[i]), acc[i]);
    short ob[8];
    #pragma unroll
    for (int i = 0; i < 8; ++i) {
        float sv = acc[i] / (1.f + __expf(-acc[i]));   // silu
        union { __hip_bfloat16 h; short s; } cvu;
        cvu.h = __float2bfloat16(sv);
        ob[i] = cvu.s;
    }
    *(bf16x8*)(u + base) = *(const bf16x8*)ob;
}

// ---------------- Segmented selective scan: thread-per-channel ----------------
// A_log is log(1..16) tiled -> A[d][s] = -(s+1): fast multiply-chain path.
// T14 async-STAGE: chunk-1 global loads into registers during chunk-0 compute.
// hseg stored as bf16 (fp32 register math; ~0.5% storage rounding).

// Pass 1: per-segment local scan from h=0; store final h + sum(dt).
__global__ __launch_bounds__(256)
void scan_part1(const _Float16* __restrict__ dtb,
                const __hip_bfloat16* __restrict__ ub,
                const float* __restrict__ dbcF,
                const float* __restrict__ A_log,
                __hip_bfloat16* __restrict__ hseg,  // [b][seg][s][DI] bf16
                float* __restrict__ dtsum)          // [b][seg][DI]
{
    __shared__ _Float16 sdt[CT][256];
    __shared__ __hip_bfloat16 su[CT][256];
    __shared__ float sB[CT][DS_];
    int t = threadIdx.x;
    int d0 = blockIdx.x * 256, seg = blockIdx.y, b = blockIdx.z;
    int d = d0 + t;
    size_t rowbase = (size_t)b * L_ + seg * SEGLEN;

    int rw0 = t >> 5, rw1 = 8 + (t >> 5);
    int c8 = (t & 31) * 8;
    int bl = t >> 4, bs = t & 15;

    bf16x8 vdt0 = *(const bf16x8*)&dtb[(rowbase + rw0) * DI_ + d0 + c8];
    bf16x8 vdt1 = *(const bf16x8*)&dtb[(rowbase + rw1) * DI_ + d0 + c8];
    bf16x8 vu0  = *(const bf16x8*)&ub [(rowbase + rw0) * DI_ + d0 + c8];
    bf16x8 vu1  = *(const bf16x8*)&ub [(rowbase + rw1) * DI_ + d0 + c8];
    float  vB   = dbcF[(rowbase + bl) * NDBC_ + DTR_ + bs];

    float A2[DS_], h[DS_];
    bool fastA = true;
    #pragma unroll
    for (int s = 0; s < DS_; ++s) {
        float a = __expf(A_log[d * DS_ + s]);
        A2[s] = -a * LOG2E;
        fastA = fastA && (fabsf(a - (float)(s + 1)) < 1e-3f);
        h[s] = 0.f;
    }
    float dts = 0.f;

    auto store_lds = [&]() {
        *(bf16x8*)&sdt[rw0][c8] = vdt0;
        *(bf16x8*)&sdt[rw1][c8] = vdt1;
        *(bf16x8*)&su[rw0][c8]  = vu0;
        *(bf16x8*)&su[rw1][c8]  = vu1;
        sB[bl][bs] = vB;
    };
    auto compute_chunk = [&]() {
        if (fastA) {
            for (int l = 0; l < CT; ++l) {
                float dtv = (float)sdt[l][t];
                float du  = dtv * __bfloat162float(su[l][t]);
                dts += dtv;
                float g = exp2f(-dtv * LOG2E);
                float r = 1.f;
                #pragma unroll
                for (int s = 0; s < DS_; ++s) {
                    r *= g;
                    h[s] = r * h[s] + du * sB[l][s];
                }
            }
        } else {
            for (int l = 0; l < CT; ++l) {
                float dtv = (float)sdt[l][t];
                float du  = dtv * __bfloat162float(su[l][t]);
                dts += dtv;
                #pragma unroll
                for (int s = 0; s < DS_; ++s)
                    h[s] = exp2f(dtv * A2[s]) * h[s] + du * sB[l][s];
            }
        }
    };

    store_lds();
    __syncthreads();

    vdt0 = *(const bf16x8*)&dtb[(rowbase + CT + rw0) * DI_ + d0 + c8];
    vdt1 = *(const bf16x8*)&dtb[(rowbase + CT + rw1) * DI_ + d0 + c8];
    vu0  = *(const bf16x8*)&ub [(rowbase + CT + rw0) * DI_ + d0 + c8];
    vu1  = *(const bf16x8*)&ub [(rowbase + CT + rw1) * DI_ + d0 + c8];
    vB   = dbcF[(rowbase + CT + bl) * NDBC_ + DTR_ + bs];

    compute_chunk();
    __syncthreads();
    store_lds();
    __syncthreads();
    compute_chunk();

    #pragma unroll
    for (int s = 0; s < DS_; ++s)
        hseg[(((size_t)b * NSEG + seg) * DS_ + s) * DI_ + d] =
            __float2bfloat16(h[s]);
    dtsum[((size_t)b * NSEG + seg) * DI_ + d] = dts;
}

// Pass 2: inter-segment scan with load-ahead prefetch (fp32 register math).
__global__ __launch_bounds__(256)
void seg_scan(__hip_bfloat16* __restrict__ hseg,
              const float* __restrict__ dtsum,
              const float* __restrict__ A_log)
{
    int idx = blockIdx.x * 256 + threadIdx.x;   // b*DI*DS, d fastest
    int d = idx & (DI_ - 1);
    int s = (idx >> 11) & 15;
    int b = idx >> 15;
    float A2 = -__expf(A_log[d * DS_ + s]) * LOG2E;
    float h = 0.f;
    size_t o = (((size_t)b * NSEG + 0) * DS_ + s) * DI_ + d;
    size_t oi = ((size_t)b * NSEG + 0) * DI_ + d;
    float pv = __bfloat162float(hseg[o]), ds = dtsum[oi];
    for (int g = 0; g < NSEG; ++g) {
        float npv = 0.f, nds = 0.f;
        if (g + 1 < NSEG) {
            npv = __bfloat162float(hseg[o + (size_t)DS_ * DI_]);
            nds = dtsum[oi + DI_];
        }
        hseg[o] = __float2bfloat16(h);
        h = exp2f(A2 * ds) * h + pv;
        pv = npv; ds = nds;
        o += (size_t)DS_ * DI_;
        oi += DI_;
    }
}

// Pass 3: re-scan with correct h_in; write y into yb_cat[row][dir*DI+d].
__global__ __launch_bounds__(256)
void scan_part2(const _Float16* __restrict__ dtb,
                const __hip_bfloat16* __restrict__ ub,
                const __hip_bfloat16* __restrict__ zs,
                const float* __restrict__ dbcF,
                const float* __restrict__ A_log,
                const float* __restrict__ Dskip,
                const __hip_bfloat16* __restrict__ hseg,
                __hip_bfloat16* __restrict__ ycat,
                int dir)
{
    __shared__ _Float16 sdt[CT][256];
    __shared__ __hip_bfloat16 su[CT][256], sz[CT][256], sy[CT][256];
    __shared__ float sB[CT][DS_], sC[CT][DS_];
    int t = threadIdx.x;
    int d0 = blockIdx.x * 256, seg = blockIdx.y, b = blockIdx.z;
    int d = d0 + t;
    size_t rowbase = (size_t)b * L_ + seg * SEGLEN;
    int ycol0 = dir * DI_ + d0;

    int rw0 = t >> 5, rw1 = 8 + (t >> 5);
    int c8 = (t & 31) * 8;
    int bl = t >> 4, bs = t & 15;

    bf16x8 vdt0 = *(const bf16x8*)&dtb[(rowbase + rw0) * DI_ + d0 + c8];
    bf16x8 vdt1 = *(const bf16x8*)&dtb[(rowbase + rw1) * DI_ + d0 + c8];
    bf16x8 vu0  = *(const bf16x8*)&ub [(rowbase + rw0) * DI_ + d0 + c8];
    bf16x8 vu1  = *(const bf16x8*)&ub [(rowbase + rw1) * DI_ + d0 + c8];
    bf16x8 vz0  = *(const bf16x8*)&zs [(rowbase + rw0) * DI_ + d0 + c8];
    bf16x8 vz1  = *(const bf16x8*)&zs [(rowbase + rw1) * DI_ + d0 + c8];
    float  vB   = dbcF[(rowbase + bl) * NDBC_ + DTR_ + bs];
    float  vC   = dbcF[(rowbase + bl) * NDBC_ + DTR_ + DS_ + bs];

    float A2[DS_], h[DS_];
    bool fastA = true;
    #pragma unroll
    for (int s = 0; s < DS_; ++s) {
        float a = __expf(A_log[d * DS_ + s]);
        A2[s] = -a * LOG2E;
        fastA = fastA && (fabsf(a - (float)(s + 1)) < 1e-3f);
        h[s] = __bfloat162float(
            hseg[(((size_t)b * NSEG + seg) * DS_ + s) * DI_ + d]);
    }
    float Dd = Dskip[d];

    auto store_lds = [&]() {
        *(bf16x8*)&sdt[rw0][c8] = vdt0;
        *(bf16x8*)&sdt[rw1][c8] = vdt1;
        *(bf16x8*)&su[rw0][c8]  = vu0;
        *(bf16x8*)&su[rw1][c8]  = vu1;
        *(bf16x8*)&sz[rw0][c8]  = vz0;
        *(bf16x8*)&sz[rw1][c8]  = vz1;
        sB[bl][bs] = vB;
        sC[bl][bs] = vC;
    };
    auto compute_chunk = [&]() {
        if (fastA) {
            for (int l = 0; l < CT; ++l) {
                float dtv = (float)sdt[l][t];
                float uu  = __bfloat162float(su[l][t]);
                float du  = dtv * uu;
                float g = exp2f(-dtv * LOG2E);
                float r = 1.f;
                float y = 0.f;
                #pragma unroll
                for (int s = 0; s < DS_; ++s) {
                    r *= g;
                    h[s] = r * h[s] + du * sB[l][s];
                    y = fmaf(h[s], sC[l][s], y);
                }
                y = (y + Dd * uu) * __bfloat162float(sz[l][t]);
                sy[l][t] = __float2bfloat16(y);
            }
        } else {
            for (int l = 0; l < CT; ++l) {
                float dtv = (float)sdt[l][t];
                float uu  = __bfloat162float(su[l][t]);
                float du  = dtv * uu;
                float y = 0.f;
                #pragma unroll
                for (int s = 0; s < DS_; ++s) {
                    h[s] = exp2f(dtv * A2[s]) * h[s] + du * sB[l][s];
                    y = fmaf(h[s], sC[l][s], y);
                }
                y = (y + Dd * uu) * __bfloat162float(sz[l][t]);
                sy[l][t] = __float2bfloat16(y);
            }
        }
    };
    auto store_y = [&](int c) {
        #pragma unroll
        for (int p2 = 0; p2 < 2; ++p2) {
            int e = t + p2 * 256;
            int row = e >> 5, cc = (e & 31) * 8;
            int lg = seg * SEGLEN + c * CT + row;
            int lw = dir ? (L_ - 1 - lg) : lg;
            *(bf16x8*)&ycat[((size_t)b * L_ + lw) * NXZ_ + ycol0 + cc] =
                *(const bf16x8*)&sy[row][cc];
        }
    };

    store_lds();
    __syncthreads();

    vdt0 = *(const bf16x8*)&dtb[(rowbase + CT + rw0) * DI_ + d0 + c8];
    vdt1 = *(const bf16x8*)&dtb[(rowbase + CT + rw1) * DI_ + d0 + c8];
    vu0  = *(const bf16x8*)&ub [(rowbase + CT + rw0) * DI_ + d0 + c8];
    vu1  = *(const bf16x8*)&ub [(rowbase + CT + rw1) * DI_ + d0 + c8];
    vz0  = *(const bf16x8*)&zs [(rowbase + CT + rw0) * DI_ + d0 + c8];
    vz1  = *(const bf16x8*)&zs [(rowbase + CT + rw1) * DI_ + d0 + c8];
    vB   = dbcF[(rowbase + CT + bl) * NDBC_ + DTR_ + bs];
    vC   = dbcF[(rowbase + CT + bl) * NDBC_ + DTR_ + DS_ + bs];

    compute_chunk();            // chunk 0 -> sy
    __syncthreads();
    store_y(0);
    store_lds();                // chunk 1 -> LDS
    __syncthreads();
    compute_chunk();            // chunk 1 -> sy
    __syncthreads();
    store_y(1);
}

extern "C" void kernel_launch(void* const* d_in, const int* in_sizes, int n_in,
                              void* d_out, int out_size, void* d_ws, size_t ws_size,
                              hipStream_t stream)
{
    (void)in_sizes; (void)n_in; (void)out_size; (void)ws_size;
    const float* x     = (const float*)d_in[0];
    const float* gamma = (const float*)d_in[1];
    const float* beta  = (const float*)d_in[2];
    float* out = (float*)d_out;

    const size_t BLDI = (size_t)B_ * L_ * DI_;      // 8,388,608

    // workspace (~131 MB); u0/pbufB/dtF time-share shreg per dir;
    // out_proj bf16 partials (16.78 MB) alias hsegB+shreg at the end.
    float* ws    = (float*)d_ws;
    float* dbcF  = ws;                               // 1.57 MB
    float* dtsum = dbcF + (size_t)B_ * L_ * NDBC_;   // 1.05 MB
    __hip_bfloat16* hsegB = (__hip_bfloat16*)(dtsum + (size_t)B_ * NSEG * DI_); // 8.39 MB
    float* shreg = (float*)(hsegB + (size_t)B_ * NSEG * DI_ * DS_);  // 16.78 MB
    __hip_bfloat16* lnb  = (__hip_bfloat16*)(shreg + BLDI / 2);
    __hip_bfloat16* ub   = lnb + (size_t)B_ * L_ * DM_;   // 16.78
    __hip_bfloat16* zs   = ub + BLDI;                     // 16.78
    __hip_bfloat16* ycat = zs + BLDI;                     // 33.55 (both dirs, K-cat)
    __hip_bfloat16* win  = ycat + (size_t)B_ * L_ * NXZ_; // 16.78 (both dirs)
    __hip_bfloat16* wocat= win + (size_t)2 * NXZ_ * DM_;  // 8.39  ([DM][2*DI])
    __hip_bfloat16* xpw  = wocat + (size_t)DM_ * NXZ_;    // 0.79 (both dirs)
    __hip_bfloat16* dtw  = xpw + (size_t)2 * NDBC_ * DI_; // 0.53 (both dirs)
    __hip_bfloat16* dbcB = dtw + (size_t)2 * DI_ * DTR_;  // 0.52 (per-dir reuse)
    // aliases of shreg (sequential lifetimes within each dir):
    __hip_bfloat16* u0b   = (__hip_bfloat16*)shreg;  // in_proj -> conv
    __hip_bfloat16* pbufB = (__hip_bfloat16*)shreg;  // xproj bf16 partials (8.4MB)
    _Float16*       dtF   = (_Float16*)shreg;        // dt gemm -> scans
    __hip_bfloat16* pout  = hsegB;                   // out bf16 partials (2 slices)

    dim3 blk(256);

    // all weights -> bf16 in a single dispatch
    cvt_all<<<12928, blk, 0, stream>>>(
        (const float*)d_in[3],  (const float*)d_in[12],
        (const float*)d_in[11], (const float*)d_in[20],
        (const float*)d_in[6],  (const float*)d_in[15],
        (const float*)d_in[7],  (const float*)d_in[16],
        win, wocat, xpw, dtw);

    ln_kernel<<<B_ * L_, blk, 0, stream>>>(x, gamma, beta, lnb);

    for (int dir = 0; dir < 2; ++dir) {
        int base = 3 + dir * 9;
        const float* conv_w  = (const float*)d_in[base + 1];
        const float* conv_b  = (const float*)d_in[base + 2];
        const float* dt_b    = (const float*)d_in[base + 5];
        const float* A_log   = (const float*)d_in[base + 6];
        const float* Dsk     = (const float*)d_in[base + 7];

        // in_proj: [u0b | silu(z)->zs] = ln(flip?) @ in_w^T  (dbuf+counted vmcnt)
        mfma_gemm<1, 0><<<dim3(NXZ_ / GBM, (B_ * L_) / GBM), blk, 0, stream>>>(
            lnb, DM_, win + (size_t)dir * NXZ_ * DM_, DM_,
            DM_, DM_, NXZ_, dir, nullptr, nullptr, u0b, zs, nullptr);

        conv_kernel<<<(B_ * L_ * DI_) / 2048, blk, 0, stream>>>(
            u0b, conv_w, conv_b, ub);

        // xproj: dbc = u @ xproj_w^T (N=96), split-K x8 -> bf16 partials
        mfma_gemm<1, 3><<<dim3(1, (B_ * L_) / GBM, KS_), blk, 0, stream>>>(
            ub, DI_, xpw + (size_t)dir * NDBC_ * DI_, DI_,
            DI_, DI_ / KS_, NDBC_, 0, nullptr, nullptr, pbufB, nullptr, nullptr);
        xproj_reduce<<<(B_ * L_ * 16) / 256, blk, 0, stream>>>(pbufB, dbcF, dbcB);

        // dt = softplus(dbc[:, :64] @ dt_w^T + dt_b) -> fp16 (shreg)
        mfma_gemm<0, 4><<<dim3(DI_ / GBM, (B_ * L_) / GBM), blk, 0, stream>>>(
            dbcB, DTR_, dtw + (size_t)dir * DI_ * DTR_, DTR_,
            DTR_, DTR_, DI_, 0, dt_b, nullptr, nullptr, nullptr, dtF);

        // segmented scan (thread-per-channel, states in registers)
        scan_part1<<<dim3(DI_ / 256, NSEG, B_), blk, 0, stream>>>(
            dtF, ub, dbcF, A_log, hsegB, dtsum);
        seg_scan<<<(B_ * DI_ * DS_) / 256, blk, 0, stream>>>(hsegB, dtsum, A_log);
        scan_part2<<<dim3(DI_ / 256, NSEG, B_), blk, 0, stream>>>(
            dtF, ub, zs, dbcF, A_log, Dsk, hsegB, ycat, dir);
    }

    // merged out_proj: split-K x2 (dbuf, 512 blocks) -> bf16 partials, then
    // out = x + 0.5*(p0+p1)
    mfma_gemm<1, 1><<<dim3(DM_ / GBM, (B_ * L_) / GBM, KO_), blk, 0, stream>>>(
        ycat, NXZ_, wocat, NXZ_, NXZ_, NXZ_ / KO_, DM_, 0,
        nullptr, nullptr, pout, nullptr, nullptr);
    out_reduce<<<(B_ * L_ * DM_) / 2048, blk, 0, stream>>>(pout, x, out);
}

// Round 25
// 328.886 us; speedup vs baseline: 1.1430x; 1.1331x over previous
//
#include <hip/hip_runtime.h>
#include <hip/hip_bf16.h>
#include <math.h>

// Problem constants
#define B_    2
#define L_    2048
#define DM_   1024      // d_model
#define DI_   2048      // d_inner
#define DS_   16        // d_state
#define DTR_  64        // dt_rank
#define NXZ_  4096      // 2*d_inner
#define NDBC_ 96        // dt_rank + 2*d_state

#define NSEG   64
#define SEGLEN 32
#define CT     16       // timesteps staged per chunk
#define KS_    8        // xproj split-K factor
#define KO_    2        // out_proj split-K factor (A/B-confirmed best)

#define LOG2E 1.4426950408889634f

typedef __attribute__((ext_vector_type(8))) short bf16x8;
typedef __attribute__((ext_vector_type(4))) float f32x4;

__device__ __forceinline__ void gload_lds16(const void* g, void* l) {
    __builtin_amdgcn_global_load_lds(
        (const __attribute__((address_space(1))) void*)g,
        (__attribute__((address_space(3))) void*)l,
        16, 0, 0);
}

__device__ __forceinline__ float bf2f(short s) {
    union { unsigned u; float f; } x;
    x.u = ((unsigned)(unsigned short)s) << 16;
    return x.f;
}

// ---------------- LayerNorm (one block per row) -> bf16 out ----------------
__global__ __launch_bounds__(256)
void ln_kernel(const float* __restrict__ x,
               const float* __restrict__ gamma,
               const float* __restrict__ beta,
               __hip_bfloat16* __restrict__ out)
{
    int row = blockIdx.x;
    int t = threadIdx.x;
    const float* xr = x + (size_t)row * DM_;
    float4 v = ((const float4*)xr)[t];
    float s  = v.x + v.y + v.z + v.w;
    float ss = v.x*v.x + v.y*v.y + v.z*v.z + v.w*v.w;
    #pragma unroll
    for (int m = 1; m < 64; m <<= 1) {
        s  += __shfl_xor(s,  m, 64);
        ss += __shfl_xor(ss, m, 64);
    }
    __shared__ float as_[4], ass_[4];
    int w = t >> 6;
    if ((t & 63) == 0) { as_[w] = s; ass_[w] = ss; }
    __syncthreads();
    s  = as_[0] + as_[1] + as_[2] + as_[3];
    ss = ass_[0] + ass_[1] + ass_[2] + ass_[3];
    float mu  = s * (1.0f / DM_);
    float var = ss * (1.0f / DM_) - mu * mu;
    float inv = rsqrtf(var + 1e-5f);
    float4 g  = ((const float4*)gamma)[t];
    float4 bt = ((const float4*)beta)[t];
    __hip_bfloat16 ob[4];
    ob[0] = __float2bfloat16((v.x - mu) * inv * g.x + bt.x);
    ob[1] = __float2bfloat16((v.y - mu) * inv * g.y + bt.y);
    ob[2] = __float2bfloat16((v.z - mu) * inv * g.z + bt.z);
    ob[3] = __float2bfloat16((v.w - mu) * inv * g.w + bt.w);
    ((ushort4*)(out + (size_t)row * DM_))[t] = *(const ushort4*)ob;
}

// ---------------- merged weight convert (all 8 weights, both dirs) ---------
__global__ __launch_bounds__(256)
void cvt_all(const float* __restrict__ inw_f, const float* __restrict__ inw_b,
             const float* __restrict__ ow_f,  const float* __restrict__ ow_b,
             const float* __restrict__ xp_f,  const float* __restrict__ xp_b,
             const float* __restrict__ dw_f,  const float* __restrict__ dw_b,
             __hip_bfloat16* __restrict__ win,
             __hip_bfloat16* __restrict__ wocat,
             __hip_bfloat16* __restrict__ xpw,
             __hip_bfloat16* __restrict__ dtw)
{
    const int N_WIN = 2 * NXZ_ * DM_;
    const int N_WO  = DM_ * NXZ_;
    const int N_XP  = 2 * NDBC_ * DI_;
    int i = (blockIdx.x * 256 + threadIdx.x) * 4;
    const float* s;
    __hip_bfloat16* dst;
    int dj;
    if (i < N_WIN) {
        int half = NXZ_ * DM_;
        s = (i < half) ? inw_f + i : inw_b + (i - half);
        dst = win; dj = i;
    } else if (i < N_WIN + N_WO) {
        int jj = i - N_WIN;
        int n = jj >> 12, c = jj & 4095;
        int dir = c >> 11, k = c & 2047;
        s = (dir ? ow_b : ow_f) + (size_t)n * DI_ + k;
        dst = wocat; dj = jj;
    } else if (i < N_WIN + N_WO + N_XP) {
        int jj = i - N_WIN - N_WO;
        int half = NDBC_ * DI_;
        s = (jj < half) ? xp_f + jj : xp_b + (jj - half);
        dst = xpw; dj = jj;
    } else {
        int jj = i - N_WIN - N_WO - N_XP;
        int half = DI_ * DTR_;
        s = (jj < half) ? dw_f + jj : dw_b + (jj - half);
        dst = dtw; dj = jj;
    }
    float4 v = *(const float4*)s;
    __hip_bfloat16 ob[4];
    ob[0] = __float2bfloat16(v.x);
    ob[1] = __float2bfloat16(v.y);
    ob[2] = __float2bfloat16(v.z);
    ob[3] = __float2bfloat16(v.w);
    *(ushort4*)(dst + dj) = *(const ushort4*)ob;
}

// ---------------- bf16 MFMA GEMM: C = A(MxK) @ W(NxK)^T ----------------
#define GBM 128
#define GBK 64
#define EPLD 132   // padded LDS row (elements) for the epilogue tile

template<int DBUF, int EPI>
__global__ __launch_bounds__(256)
void mfma_gemm(const __hip_bfloat16* __restrict__ A, int lda,
               const __hip_bfloat16* __restrict__ W, int ldw,
               int K, int Kslice, int Nw, int flipA,
               const float* __restrict__ aux,
               float* __restrict__ out0,
               __hip_bfloat16* __restrict__ ob1,
               __hip_bfloat16* __restrict__ ob2,
               _Float16* __restrict__ oh)
{
    __shared__ __attribute__((aligned(16))) char smem[DBUF ? 65536 : 33792];
    const int BOFF = DBUF ? 32768 : 16384;
    int t = threadIdx.x;
    int lane = t & 63, wid = t >> 6;
    int wm = wid >> 1, wn = wid & 1;

    // 2D-chunked XCD-aware swizzle (bijective for all our grids).
    int bx, by;
    {
        int gx = gridDim.x, gy = gridDim.y;
        int nwg = gx * gy;
        int orig = blockIdx.y * gx + blockIdx.x;
        int xcd = orig & 7;
        int c = orig >> 3;
        int npx = nwg >> 3;              // blocks per XCD
        int Wc = gx < 8 ? gx : 8;        // region width (tiles)
        int Hc = npx / Wc;               // region height
        int regx = gx / Wc;              // regions across
        int rx = xcd % regx, ry = xcd / regx;
        bx = rx * Wc + (c % Wc);
        by = ry * Hc + (c / Wc);
    }
    int m0 = by * GBM, n0 = bx * GBM;
    int kz = blockIdx.z;
    int k_begin = kz * Kslice;
    int k_end   = (k_begin + Kslice < K) ? (k_begin + Kslice) : K;
    int ktiles  = (k_end - k_begin) / GBK;

    f32x4 acc[4][4];
    #pragma unroll
    for (int i = 0; i < 4; ++i)
        #pragma unroll
        for (int j = 0; j < 4; ++j)
            acc[i][j] = (f32x4){0.f, 0.f, 0.f, 0.f};

    int arows[4], brows[4], cbs[4];
    #pragma unroll
    for (int p = 0; p < 4; ++p) {
        int o = p * 4096 + t * 16;
        int l = o ^ (((o >> 7) & 7) << 4);
        int r = l >> 7, cb = l & 127;
        int gr = m0 + r;
        if (flipA) gr = (gr & ~(L_ - 1)) | ((L_ - 1) - (gr & (L_ - 1)));
        arows[p] = gr;
        int wr = n0 + r; if (wr >= Nw) wr = Nw - 1;   // clamp (N=96 case)
        brows[p] = wr;
        cbs[p] = cb;
    }

    #define STAGE(buf, k0)                                                        \
        {                                                                         \
            _Pragma("unroll")                                                     \
            for (int p = 0; p < 4; ++p) {                                         \
                int o = p * 4096 + t * 16;                                        \
                const char* gA = (const char*)(A + (size_t)arows[p] * lda + (k0)) \
                                 + cbs[p];                                        \
                gload_lds16(gA, smem + (buf) * 16384 + o);                        \
                const char* gB = (const char*)(W + (size_t)brows[p] * ldw + (k0)) \
                                 + cbs[p];                                        \
                gload_lds16(gB, smem + BOFF + (buf) * 16384 + o);                 \
            }                                                                     \
        }

    auto compute_tile = [&](int pbv) {
        char* bA = smem + pbv * 16384;
        char* bB = smem + BOFF + pbv * 16384;
        #pragma unroll
        for (int ks = 0; ks < 2; ++ks) {
            bf16x8 af[4], bfv[4];
            #pragma unroll
            for (int f = 0; f < 4; ++f) {
                int rowA = wm * 64 + f * 16 + (lane & 15);
                int lA = rowA * 128 + ks * 64 + ((lane >> 4) << 4);
                int pA = lA ^ ((rowA & 7) << 4);
                af[f] = *(const bf16x8*)(bA + pA);
                int rowB = wn * 64 + f * 16 + (lane & 15);
                int lB = rowB * 128 + ks * 64 + ((lane >> 4) << 4);
                int pB = lB ^ ((rowB & 7) << 4);
                bfv[f] = *(const bf16x8*)(bB + pB);
            }
            #pragma unroll
            for (int i = 0; i < 4; ++i)
                #pragma unroll
                for (int j = 0; j < 4; ++j)
                    acc[i][j] = __builtin_amdgcn_mfma_f32_16x16x32_bf16(
                        af[i], bfv[j], acc[i][j], 0, 0, 0);
        }
    };

    if (DBUF) {
        STAGE(0, k_begin);
        int pb = 0;
        for (int kt = 0; kt < ktiles; ++kt) {
            if (kt + 1 < ktiles) {
                STAGE(pb ^ 1, k_begin + (kt + 1) * GBK);
                asm volatile("s_waitcnt vmcnt(8)" ::: "memory");
            } else {
                asm volatile("s_waitcnt vmcnt(0)" ::: "memory");
            }
            __builtin_amdgcn_s_barrier();
            compute_tile(pb);
            __builtin_amdgcn_s_barrier();
            pb ^= 1;
        }
    } else {
        for (int kt = 0; kt < ktiles; ++kt) {
            STAGE(0, k_begin + kt * GBK);
            __syncthreads();
            compute_tile(0);
            __syncthreads();
        }
    }
    #undef STAGE

    // Epilogue. C/D layout: col = lane&15, row = (lane>>4)*4 + reg.
    if (EPI == 0) {
        bool zh = (n0 >= DI_);
        __hip_bfloat16* tile = (__hip_bfloat16*)smem;
        __syncthreads();
        #pragma unroll
        for (int i = 0; i < 4; ++i)
            #pragma unroll
            for (int j = 0; j < 4; ++j) {
                int col = wn * 64 + j * 16 + (lane & 15);
                #pragma unroll
                for (int r = 0; r < 4; ++r) {
                    int row = wm * 64 + i * 16 + ((lane >> 4) << 2) + r;
                    float v = acc[i][j][r];
                    if (zh) v = v / (1.f + __expf(-v));
                    tile[row * EPLD + col] = __float2bfloat16(v);
                }
            }
        __syncthreads();
        __hip_bfloat16* dst = zh ? ob2 : ob1;
        int nb = zh ? n0 - DI_ : n0;
        #pragma unroll
        for (int it = 0; it < 8; ++it) {
            int row = it * 16 + (t >> 4);
            int c8 = (t & 15) * 8;
            bf16x8 vv = *(const bf16x8*)&tile[row * EPLD + c8];
            *(bf16x8*)(dst + (size_t)(m0 + row) * DI_ + nb + c8) = vv;
        }
    } else if (EPI == 4) {
        _Float16* tile = (_Float16*)smem;
        float bias_j[4];
        #pragma unroll
        for (int j = 0; j < 4; ++j)
            bias_j[j] = aux[n0 + wn * 64 + j * 16 + (lane & 15)];
        __syncthreads();
        #pragma unroll
        for (int i = 0; i < 4; ++i)
            #pragma unroll
            for (int j = 0; j < 4; ++j) {
                int col = wn * 64 + j * 16 + (lane & 15);
                #pragma unroll
                for (int r = 0; r < 4; ++r) {
                    int row = wm * 64 + i * 16 + ((lane >> 4) << 2) + r;
                    float v = acc[i][j][r] + bias_j[j];
                    float sp = fmaxf(v, 0.f) + __logf(1.f + __expf(-fabsf(v)));
                    tile[row * EPLD + col] = (_Float16)sp;
                }
            }
        __syncthreads();
        #pragma unroll
        for (int it = 0; it < 8; ++it) {
            int row = it * 16 + (t >> 4);
            int c8 = (t & 15) * 8;
            bf16x8 vv = *(const bf16x8*)&tile[row * EPLD + c8];
            *(bf16x8*)(oh + (size_t)(m0 + row) * DI_ + n0 + c8) = vv;
        }
    } else if (EPI == 3) {
        // xproj split-K partial -> bf16, LDS-coalesced (padded ldc=128)
        __hip_bfloat16* tile = (__hip_bfloat16*)smem;
        __syncthreads();
        #pragma unroll
        for (int i = 0; i < 4; ++i)
            #pragma unroll
            for (int j = 0; j < 4; ++j) {
                int col = wn * 64 + j * 16 + (lane & 15);
                #pragma unroll
                for (int r = 0; r < 4; ++r) {
                    int row = wm * 64 + i * 16 + ((lane >> 4) << 2) + r;
                    tile[row * EPLD + col] = __float2bfloat16(acc[i][j][r]);
                }
            }
        __syncthreads();
        #pragma unroll
        for (int it = 0; it < 8; ++it) {
            int row = it * 16 + (t >> 4);
            int c8 = (t & 15) * 8;
            bf16x8 vv = *(const bf16x8*)&tile[row * EPLD + c8];
            *(bf16x8*)(ob1 + ((size_t)kz * (B_ * L_) + m0 + row) * 128 + n0 + c8) = vv;
        }
    } else { // EPI == 1: out_proj split-K bf16 partial [kz][M][DM]
        #pragma unroll
        for (int i = 0; i < 4; ++i) {
            #pragma unroll
            for (int j = 0; j < 4; ++j) {
                f32x4 a4 = acc[i][j];
                int gn = n0 + wn * 64 + j * 16 + (lane & 15);
                #pragma unroll
                for (int r = 0; r < 4; ++r) {
                    int gm = m0 + wm * 64 + i * 16 + ((lane >> 4) << 2) + r;
                    ob1[((size_t)kz * (B_ * L_) + gm) * DM_ + gn] =
                        __float2bfloat16(a4[r]);
                }
            }
        }
    }
}

// ---------------- out_proj split-K(x2) reduce + residual ----------------
__global__ __launch_bounds__(256)
void out_reduce(const __hip_bfloat16* __restrict__ pout,
                const float* __restrict__ x,
                float* __restrict__ out)
{
    const size_t BLDM = (size_t)B_ * L_ * DM_;
    size_t i = ((size_t)blockIdx.x * 256 + threadIdx.x) * 8;
    bf16x8 p0 = *(const bf16x8*)(pout + i);
    bf16x8 p1 = *(const bf16x8*)(pout + BLDM + i);
    float4 x0 = *(const float4*)(x + i);
    float4 x1 = *(const float4*)(x + i + 4);
    float4 o0, o1;
    o0.x = x0.x + 0.5f * (bf2f(p0[0]) + bf2f(p1[0]));
    o0.y = x0.y + 0.5f * (bf2f(p0[1]) + bf2f(p1[1]));
    o0.z = x0.z + 0.5f * (bf2f(p0[2]) + bf2f(p1[2]));
    o0.w = x0.w + 0.5f * (bf2f(p0[3]) + bf2f(p1[3]));
    o1.x = x1.x + 0.5f * (bf2f(p0[4]) + bf2f(p1[4]));
    o1.y = x1.y + 0.5f * (bf2f(p0[5]) + bf2f(p1[5]));
    o1.z = x1.z + 0.5f * (bf2f(p0[6]) + bf2f(p1[6]));
    o1.w = x1.w + 0.5f * (bf2f(p0[7]) + bf2f(p1[7]));
    *(float4*)(out + i) = o0;
    *(float4*)(out + i + 4) = o1;
}

// ---------------- xproj split-K reduce (bf16 partials, vectorized) ---------
__global__ __launch_bounds__(256)
void xproj_reduce(const __hip_bfloat16* __restrict__ pbufB,
                  float* __restrict__ dbcF,
                  __hip_bfloat16* __restrict__ dbcB)
{
    int idx = blockIdx.x * 256 + threadIdx.x;   // (B*L) * 16 threads-of-8
    int m = idx >> 4;
    int n8 = (idx & 15) * 8;
    float sum[8] = {0.f,0.f,0.f,0.f,0.f,0.f,0.f,0.f};
    #pragma unroll
    for (int k = 0; k < KS_; ++k) {
        bf16x8 v = *(const bf16x8*)&pbufB[((size_t)k * (B_ * L_) + m) * 128 + n8];
        #pragma unroll
        for (int i = 0; i < 8; ++i) sum[i] += bf2f(v[i]);
    }
    #pragma unroll
    for (int i = 0; i < 8; ++i) {
        int n = n8 + i;
        if (n < NDBC_) dbcF[(size_t)m * NDBC_ + n] = sum[i];
    }
    if (n8 < DTR_) {
        short ob[8];
        #pragma unroll
        for (int i = 0; i < 8; ++i) {
            union { __hip_bfloat16 h; short s; } cv;
            cv.h = __float2bfloat16(sum[i]);
            ob[i] = cv.s;
        }
        *(bf16x8*)&dbcB[(size_t)m * DTR_ + n8] = *(const bf16x8*)ob;
    }
}

// ---------------- Causal depthwise conv (width 4) + bias + SiLU ----------------
// L-blocked: each thread produces 4 consecutive rows x 8 channels, loading
// 7 rows once (4 -> 1.75 loads/row). l0 is block-uniform -> no divergence.
__global__ __launch_bounds__(256)
void conv_kernel(const __hip_bfloat16* __restrict__ u0,
                 const float* __restrict__ cw,
                 const float* __restrict__ cb,
                 __hip_bfloat16* __restrict__ u)
{
    int tid = blockIdx.x * 256 + threadIdx.x;      // (B*L/4) * (DI/8) threads
    int dcol = (tid & (DI_ / 8 - 1)) * 8;          // channel group base
    int r0 = (tid >> 8) * 4;                       // global row base (DI_/8==256)
    int l0 = r0 & (L_ - 1);                        // block-uniform
    size_t base = (size_t)r0 * DI_ + dcol;

    float4 wv[8];
    float cb8[8];
    #pragma unroll
    for (int i = 0; i < 8; ++i) {
        wv[i]  = ((const float4*)cw)[dcol + i];
        cb8[i] = cb[dcol + i];
    }

    bf16x8 v[7];
    #pragma unroll
    for (int j = 0; j < 7; ++j) {
        v[j] = (bf16x8){0,0,0,0,0,0,0,0};
        if (l0 - 3 + j >= 0)
            v[j] = *(const bf16x8*)(u0 + base + (size_t)(j - 3) * DI_);
    }

    #pragma unroll
    for (int k = 0; k < 4; ++k) {
        float acc[8];
        #pragma unroll
        for (int i = 0; i < 8; ++i) acc[i] = cb8[i];
        #pragma unroll
        for (int jp = 0; jp < 4; ++jp) {           // tap jp: weight comp jp, row v[k+jp]
            if (l0 + k - 3 + jp >= 0) {
                bf16x8 vv = v[k + jp];
                #pragma unroll
                for (int i = 0; i < 8; ++i) {
                    float w = (jp == 0) ? wv[i].x : (jp == 1) ? wv[i].y
                              : (jp == 2) ? wv[i].z : wv[i].w;
                    acc[i] = fmaf(w, bf2f(vv[i]), acc[i]);
                }
            }
        }
        short ob[8];
        #pragma unroll
        for (int i = 0; i < 8; ++i) {
            float sv = acc[i] / (1.f + __expf(-acc[i]));   // silu
            union { __hip_bfloat16 h; short s; } cu;
            cu.h = __float2bfloat16(sv);
            ob[i] = cu.s;
        }
        *(bf16x8*)(u + base + (size_t)k * DI_) = *(const bf16x8*)ob;
    }
}

// ---------------- Segmented selective scan: thread-per-channel ----------------
// A_log is log(1..16) tiled -> A[d][s] = -(s+1): fast multiply-chain path.
// T14 async-STAGE: chunk-1 global loads into registers during chunk-0 compute.
// hseg stored as bf16 (fp32 register math; ~0.5% storage rounding).

// Pass 1: per-segment local scan from h=0; store final h + sum(dt).
__global__ __launch_bounds__(256)
void scan_part1(const _Float16* __restrict__ dtb,
                const __hip_bfloat16* __restrict__ ub,
                const float* __restrict__ dbcF,
                const float* __restrict__ A_log,
                __hip_bfloat16* __restrict__ hseg,  // [b][seg][s][DI] bf16
                float* __restrict__ dtsum)          // [b][seg][DI]
{
    __shared__ _Float16 sdt[CT][256];
    __shared__ __hip_bfloat16 su[CT][256];
    __shared__ float sB[CT][DS_];
    int t = threadIdx.x;
    int d0 = blockIdx.x * 256, seg = blockIdx.y, b = blockIdx.z;
    int d = d0 + t;
    size_t rowbase = (size_t)b * L_ + seg * SEGLEN;

    int rw0 = t >> 5, rw1 = 8 + (t >> 5);
    int c8 = (t & 31) * 8;
    int bl = t >> 4, bs = t & 15;

    bf16x8 vdt0 = *(const bf16x8*)&dtb[(rowbase + rw0) * DI_ + d0 + c8];
    bf16x8 vdt1 = *(const bf16x8*)&dtb[(rowbase + rw1) * DI_ + d0 + c8];
    bf16x8 vu0  = *(const bf16x8*)&ub [(rowbase + rw0) * DI_ + d0 + c8];
    bf16x8 vu1  = *(const bf16x8*)&ub [(rowbase + rw1) * DI_ + d0 + c8];
    float  vB   = dbcF[(rowbase + bl) * NDBC_ + DTR_ + bs];

    float A2[DS_], h[DS_];
    bool fastA = true;
    #pragma unroll
    for (int s = 0; s < DS_; ++s) {
        float a = __expf(A_log[d * DS_ + s]);
        A2[s] = -a * LOG2E;
        fastA = fastA && (fabsf(a - (float)(s + 1)) < 1e-3f);
        h[s] = 0.f;
    }
    float dts = 0.f;

    auto store_lds = [&]() {
        *(bf16x8*)&sdt[rw0][c8] = vdt0;
        *(bf16x8*)&sdt[rw1][c8] = vdt1;
        *(bf16x8*)&su[rw0][c8]  = vu0;
        *(bf16x8*)&su[rw1][c8]  = vu1;
        sB[bl][bs] = vB;
    };
    auto compute_chunk = [&]() {
        if (fastA) {
            for (int l = 0; l < CT; ++l) {
                float dtv = (float)sdt[l][t];
                float du  = dtv * __bfloat162float(su[l][t]);
                dts += dtv;
                float g = exp2f(-dtv * LOG2E);
                float r = 1.f;
                #pragma unroll
                for (int s = 0; s < DS_; ++s) {
                    r *= g;
                    h[s] = r * h[s] + du * sB[l][s];
                }
            }
        } else {
            for (int l = 0; l < CT; ++l) {
                float dtv = (float)sdt[l][t];
                float du  = dtv * __bfloat162float(su[l][t]);
                dts += dtv;
                #pragma unroll
                for (int s = 0; s < DS_; ++s)
                    h[s] = exp2f(dtv * A2[s]) * h[s] + du * sB[l][s];
            }
        }
    };

    store_lds();
    __syncthreads();

    vdt0 = *(const bf16x8*)&dtb[(rowbase + CT + rw0) * DI_ + d0 + c8];
    vdt1 = *(const bf16x8*)&dtb[(rowbase + CT + rw1) * DI_ + d0 + c8];
    vu0  = *(const bf16x8*)&ub [(rowbase + CT + rw0) * DI_ + d0 + c8];
    vu1  = *(const bf16x8*)&ub [(rowbase + CT + rw1) * DI_ + d0 + c8];
    vB   = dbcF[(rowbase + CT + bl) * NDBC_ + DTR_ + bs];

    compute_chunk();
    __syncthreads();
    store_lds();
    __syncthreads();
    compute_chunk();

    #pragma unroll
    for (int s = 0; s < DS_; ++s)
        hseg[(((size_t)b * NSEG + seg) * DS_ + s) * DI_ + d] =
            __float2bfloat16(h[s]);
    dtsum[((size_t)b * NSEG + seg) * DI_ + d] = dts;
}

// Pass 2: inter-segment scan with load-ahead prefetch (fp32 register math).
__global__ __launch_bounds__(256)
void seg_scan(__hip_bfloat16* __restrict__ hseg,
              const float* __restrict__ dtsum,
              const float* __restrict__ A_log)
{
    int idx = blockIdx.x * 256 + threadIdx.x;   // b*DI*DS, d fastest
    int d = idx & (DI_ - 1);
    int s = (idx >> 11) & 15;
    int b = idx >> 15;
    float A2 = -__expf(A_log[d * DS_ + s]) * LOG2E;
    float h = 0.f;
    size_t o = (((size_t)b * NSEG + 0) * DS_ + s) * DI_ + d;
    size_t oi = ((size_t)b * NSEG + 0) * DI_ + d;
    float pv = __bfloat162float(hseg[o]), ds = dtsum[oi];
    for (int g = 0; g < NSEG; ++g) {
        float npv = 0.f, nds = 0.f;
        if (g + 1 < NSEG) {
            npv = __bfloat162float(hseg[o + (size_t)DS_ * DI_]);
            nds = dtsum[oi + DI_];
        }
        hseg[o] = __float2bfloat16(h);
        h = exp2f(A2 * ds) * h + pv;
        pv = npv; ds = nds;
        o += (size_t)DS_ * DI_;
        oi += DI_;
    }
}

// Pass 3: re-scan with correct h_in; write y into yb_cat[row][dir*DI+d].
__global__ __launch_bounds__(256)
void scan_part2(const _Float16* __restrict__ dtb,
                const __hip_bfloat16* __restrict__ ub,
                const __hip_bfloat16* __restrict__ zs,
                const float* __restrict__ dbcF,
                const float* __restrict__ A_log,
                const float* __restrict__ Dskip,
                const __hip_bfloat16* __restrict__ hseg,
                __hip_bfloat16* __restrict__ ycat,
                int dir)
{
    __shared__ _Float16 sdt[CT][256];
    __shared__ __hip_bfloat16 su[CT][256], sz[CT][256], sy[CT][256];
    __shared__ float sB[CT][DS_], sC[CT][DS_];
    int t = threadIdx.x;
    int d0 = blockIdx.x * 256, seg = blockIdx.y, b = blockIdx.z;
    int d = d0 + t;
    size_t rowbase = (size_t)b * L_ + seg * SEGLEN;
    int ycol0 = dir * DI_ + d0;

    int rw0 = t >> 5, rw1 = 8 + (t >> 5);
    int c8 = (t & 31) * 8;
    int bl = t >> 4, bs = t & 15;

    bf16x8 vdt0 = *(const bf16x8*)&dtb[(rowbase + rw0) * DI_ + d0 + c8];
    bf16x8 vdt1 = *(const bf16x8*)&dtb[(rowbase + rw1) * DI_ + d0 + c8];
    bf16x8 vu0  = *(const bf16x8*)&ub [(rowbase + rw0) * DI_ + d0 + c8];
    bf16x8 vu1  = *(const bf16x8*)&ub [(rowbase + rw1) * DI_ + d0 + c8];
    bf16x8 vz0  = *(const bf16x8*)&zs [(rowbase + rw0) * DI_ + d0 + c8];
    bf16x8 vz1  = *(const bf16x8*)&zs [(rowbase + rw1) * DI_ + d0 + c8];
    float  vB   = dbcF[(rowbase + bl) * NDBC_ + DTR_ + bs];
    float  vC   = dbcF[(rowbase + bl) * NDBC_ + DTR_ + DS_ + bs];

    float A2[DS_], h[DS_];
    bool fastA = true;
    #pragma unroll
    for (int s = 0; s < DS_; ++s) {
        float a = __expf(A_log[d * DS_ + s]);
        A2[s] = -a * LOG2E;
        fastA = fastA && (fabsf(a - (float)(s + 1)) < 1e-3f);
        h[s] = __bfloat162float(
            hseg[(((size_t)b * NSEG + seg) * DS_ + s) * DI_ + d]);
    }
    float Dd = Dskip[d];

    auto store_lds = [&]() {
        *(bf16x8*)&sdt[rw0][c8] = vdt0;
        *(bf16x8*)&sdt[rw1][c8] = vdt1;
        *(bf16x8*)&su[rw0][c8]  = vu0;
        *(bf16x8*)&su[rw1][c8]  = vu1;
        *(bf16x8*)&sz[rw0][c8]  = vz0;
        *(bf16x8*)&sz[rw1][c8]  = vz1;
        sB[bl][bs] = vB;
        sC[bl][bs] = vC;
    };
    auto compute_chunk = [&]() {
        if (fastA) {
            for (int l = 0; l < CT; ++l) {
                float dtv = (float)sdt[l][t];
                float uu  = __bfloat162float(su[l][t]);
                float du  = dtv * uu;
                float g = exp2f(-dtv * LOG2E);
                float r = 1.f;
                float y = 0.f;
                #pragma unroll
                for (int s = 0; s < DS_; ++s) {
                    r *= g;
                    h[s] = r * h[s] + du * sB[l][s];
                    y = fmaf(h[s], sC[l][s], y);
                }
                y = (y + Dd * uu) * __bfloat162float(sz[l][t]);
                sy[l][t] = __float2bfloat16(y);
            }
        } else {
            for (int l = 0; l < CT; ++l) {
                float dtv = (float)sdt[l][t];
                float uu  = __bfloat162float(su[l][t]);
                float du  = dtv * uu;
                float y = 0.f;
                #pragma unroll
                for (int s = 0; s < DS_; ++s) {
                    h[s] = exp2f(dtv * A2[s]) * h[s] + du * sB[l][s];
                    y = fmaf(h[s], sC[l][s], y);
                }
                y = (y + Dd * uu) * __bfloat162float(sz[l][t]);
                sy[l][t] = __float2bfloat16(y);
            }
        }
    };
    auto store_y = [&](int c) {
        #pragma unroll
        for (int p2 = 0; p2 < 2; ++p2) {
            int e = t + p2 * 256;
            int row = e >> 5, cc = (e & 31) * 8;
            int lg = seg * SEGLEN + c * CT + row;
            int lw = dir ? (L_ - 1 - lg) : lg;
            *(bf16x8*)&ycat[((size_t)b * L_ + lw) * NXZ_ + ycol0 + cc] =
                *(const bf16x8*)&sy[row][cc];
        }
    };

    store_lds();
    __syncthreads();

    vdt0 = *(const bf16x8*)&dtb[(rowbase + CT + rw0) * DI_ + d0 + c8];
    vdt1 = *(const bf16x8*)&dtb[(rowbase + CT + rw1) * DI_ + d0 + c8];
    vu0  = *(const bf16x8*)&ub [(rowbase + CT + rw0) * DI_ + d0 + c8];
    vu1  = *(const bf16x8*)&ub [(rowbase + CT + rw1) * DI_ + d0 + c8];
    vz0  = *(const bf16x8*)&zs [(rowbase + CT + rw0) * DI_ + d0 + c8];
    vz1  = *(const bf16x8*)&zs [(rowbase + CT + rw1) * DI_ + d0 + c8];
    vB   = dbcF[(rowbase + CT + bl) * NDBC_ + DTR_ + bs];
    vC   = dbcF[(rowbase + CT + bl) * NDBC_ + DTR_ + DS_ + bs];

    compute_chunk();            // chunk 0 -> sy
    __syncthreads();
    store_y(0);
    store_lds();                // chunk 1 -> LDS
    __syncthreads();
    compute_chunk();            // chunk 1 -> sy
    __syncthreads();
    store_y(1);
}

extern "C" void kernel_launch(void* const* d_in, const int* in_sizes, int n_in,
                              void* d_out, int out_size, void* d_ws, size_t ws_size,
                              hipStream_t stream)
{
    (void)in_sizes; (void)n_in; (void)out_size; (void)ws_size;
    const float* x     = (const float*)d_in[0];
    const float* gamma = (const float*)d_in[1];
    const float* beta  = (const float*)d_in[2];
    float* out = (float*)d_out;

    const size_t BLDI = (size_t)B_ * L_ * DI_;      // 8,388,608

    // workspace (~131 MB); u0/pbufB/dtF time-share shreg per dir;
    // out_proj bf16 partials (16.78 MB) alias hsegB+shreg at the end.
    float* ws    = (float*)d_ws;
    float* dbcF  = ws;                               // 1.57 MB
    float* dtsum = dbcF + (size_t)B_ * L_ * NDBC_;   // 1.05 MB
    __hip_bfloat16* hsegB = (__hip_bfloat16*)(dtsum + (size_t)B_ * NSEG * DI_); // 8.39 MB
    float* shreg = (float*)(hsegB + (size_t)B_ * NSEG * DI_ * DS_);  // 16.78 MB
    __hip_bfloat16* lnb  = (__hip_bfloat16*)(shreg + BLDI / 2);
    __hip_bfloat16* ub   = lnb + (size_t)B_ * L_ * DM_;   // 16.78
    __hip_bfloat16* zs   = ub + BLDI;                     // 16.78
    __hip_bfloat16* ycat = zs + BLDI;                     // 33.55 (both dirs, K-cat)
    __hip_bfloat16* win  = ycat + (size_t)B_ * L_ * NXZ_; // 16.78 (both dirs)
    __hip_bfloat16* wocat= win + (size_t)2 * NXZ_ * DM_;  // 8.39  ([DM][2*DI])
    __hip_bfloat16* xpw  = wocat + (size_t)DM_ * NXZ_;    // 0.79 (both dirs)
    __hip_bfloat16* dtw  = xpw + (size_t)2 * NDBC_ * DI_; // 0.53 (both dirs)
    __hip_bfloat16* dbcB = dtw + (size_t)2 * DI_ * DTR_;  // 0.52 (per-dir reuse)
    // aliases of shreg (sequential lifetimes within each dir):
    __hip_bfloat16* u0b   = (__hip_bfloat16*)shreg;  // in_proj -> conv
    __hip_bfloat16* pbufB = (__hip_bfloat16*)shreg;  // xproj bf16 partials (8.4MB)
    _Float16*       dtF   = (_Float16*)shreg;        // dt gemm -> scans
    __hip_bfloat16* pout  = hsegB;                   // out bf16 partials (2 slices)

    dim3 blk(256);

    // all weights -> bf16 in a single dispatch
    cvt_all<<<12928, blk, 0, stream>>>(
        (const float*)d_in[3],  (const float*)d_in[12],
        (const float*)d_in[11], (const float*)d_in[20],
        (const float*)d_in[6],  (const float*)d_in[15],
        (const float*)d_in[7],  (const float*)d_in[16],
        win, wocat, xpw, dtw);

    ln_kernel<<<B_ * L_, blk, 0, stream>>>(x, gamma, beta, lnb);

    for (int dir = 0; dir < 2; ++dir) {
        int base = 3 + dir * 9;
        const float* conv_w  = (const float*)d_in[base + 1];
        const float* conv_b  = (const float*)d_in[base + 2];
        const float* dt_b    = (const float*)d_in[base + 5];
        const float* A_log   = (const float*)d_in[base + 6];
        const float* Dsk     = (const float*)d_in[base + 7];

        // in_proj: [u0b | silu(z)->zs] = ln(flip?) @ in_w^T  (dbuf+counted vmcnt)
        mfma_gemm<1, 0><<<dim3(NXZ_ / GBM, (B_ * L_) / GBM), blk, 0, stream>>>(
            lnb, DM_, win + (size_t)dir * NXZ_ * DM_, DM_,
            DM_, DM_, NXZ_, dir, nullptr, nullptr, u0b, zs, nullptr);

        // causal conv + silu (L-blocked: 4 rows/thread)
        conv_kernel<<<(B_ * L_ * DI_) / 8192, blk, 0, stream>>>(
            u0b, conv_w, conv_b, ub);

        // xproj: dbc = u @ xproj_w^T (N=96), split-K x8 -> bf16 partials
        mfma_gemm<1, 3><<<dim3(1, (B_ * L_) / GBM, KS_), blk, 0, stream>>>(
            ub, DI_, xpw + (size_t)dir * NDBC_ * DI_, DI_,
            DI_, DI_ / KS_, NDBC_, 0, nullptr, nullptr, pbufB, nullptr, nullptr);
        xproj_reduce<<<(B_ * L_ * 16) / 256, blk, 0, stream>>>(pbufB, dbcF, dbcB);

        // dt = softplus(dbc[:, :64] @ dt_w^T + dt_b) -> fp16 (shreg)
        mfma_gemm<0, 4><<<dim3(DI_ / GBM, (B_ * L_) / GBM), blk, 0, stream>>>(
            dbcB, DTR_, dtw + (size_t)dir * DI_ * DTR_, DTR_,
            DTR_, DTR_, DI_, 0, dt_b, nullptr, nullptr, nullptr, dtF);

        // segmented scan (thread-per-channel, states in registers)
        scan_part1<<<dim3(DI_ / 256, NSEG, B_), blk, 0, stream>>>(
            dtF, ub, dbcF, A_log, hsegB, dtsum);
        seg_scan<<<(B_ * DI_ * DS_) / 256, blk, 0, stream>>>(hsegB, dtsum, A_log);
        scan_part2<<<dim3(DI_ / 256, NSEG, B_), blk, 0, stream>>>(
            dtF, ub, zs, dbcF, A_log, Dsk, hsegB, ycat, dir);
    }

    // merged out_proj: split-K x2 (dbuf, 512 blocks) -> bf16 partials, then
    // out = x + 0.5*(p0+p1)
    mfma_gemm<1, 1><<<dim3(DM_ / GBM, (B_ * L_) / GBM, KO_), blk, 0, stream>>>(
        ycat, NXZ_, wocat, NXZ_, NXZ_, NXZ_ / KO_, DM_, 0,
        nullptr, nullptr, pout, nullptr, nullptr);
    out_reduce<<<(B_ * L_ * DM_) / 2048, blk, 0, stream>>>(pout, x, out);
}